// Round 2
// baseline (1528.756 us; speedup 1.0000x reference)
//
#include <hip/hip_runtime.h>
#include <cstdint>
#include <cstddef>

// AdaptiveSparseSelfAttention — round 10: qkv GEMM moved from f32 VALU (157 TF
// pipe, ~110 us) to bf16 MFMA with 3-level split + 6-term ladder (error ~2^-24,
// f32-equivalent — same ladder attn's QK^T uses, so top-64 selection is
// unaffected; V-part blocks use 2-level/3-term since V rounds to bf16 anyway).
// Epilogue scatter layout (KF/VF/Qf32) preserved VERBATIM by dumping MFMA accs
// through a [128][132] f32 LDS scratch and re-reading in the original (ti,tj)
// 8x8-per-thread order. attn_mfma and out_mfma are byte-identical to R9.
// New prep buffers appended past the old 68.2 MB layout; launcher guards on
// ws_size and falls back to the f32 qkv_gemm if the workspace is too small.
//
// ws layout (98,041,856 B total when big path active):
//   Qf32 f32  [32][2048][64]                4,194,304 f  @ short 0
//   KF   bf16 [32][128 kt][3][2][64][8]    12,582,912 s  @ short 8,388,608
//   VF   bf16 [32][64 cc][4 dt][64][8]      4,194,304 s  @ short 20,971,520
//   HOS  bf16 [2 lev][8192][512]            8,388,608 s  @ short 25,165,824
//   WoS  bf16 [2 lev][512][512]               524,288 s  @ short 33,554,432
//   WqS  bf16 [3 lev][1536][512]            2,359,296 s  @ short 34,078,720
//   XS   bf16 [3 lev][8192][512]           12,582,912 s  @ short 36,438,016

#define TSEQ 2048

typedef __attribute__((ext_vector_type(8))) short bf8;
typedef __attribute__((ext_vector_type(4))) float f32x4;

#define MFMA16(A, B, C) \
  C = __builtin_amdgcn_mfma_f32_16x16x32_bf16(A, B, C, 0, 0, 0)

static __device__ __forceinline__ short f2bf(float f) {
  unsigned u = __float_as_uint(f);
  u += 0x7FFFu + ((u >> 16) & 1u);
  return (short)(u >> 16);
}
static __device__ __forceinline__ float bf2f(short s) {
  return __uint_as_float(((unsigned)(unsigned short)s) << 16);
}

// ---------------------------------------- prep: transpose + split weight matrix
// W[K][N] -> out[lev][N][K], lev stride N*K (2 levels, for Wout)
__global__ __launch_bounds__(256) void transpose_split(
    const float* __restrict__ W, short* __restrict__ out, int K, int N) {
  __shared__ float tile[32][129];
  const int t = threadIdx.x;
  const int nb = blockIdx.x * 128, kb = blockIdx.y * 32;
#pragma unroll
  for (int c = 0; c < 4; ++c) {
    const int flat = c * 256 + t;
    const int r = flat >> 5, nq = (flat & 31) * 4;
    const float4 g = *reinterpret_cast<const float4*>(&W[(size_t)(kb + r) * N + nb + nq]);
    tile[r][nq] = g.x; tile[r][nq + 1] = g.y;
    tile[r][nq + 2] = g.z; tile[r][nq + 3] = g.w;
  }
  __syncthreads();
  const int n = t >> 1, kh = (t & 1) * 16;
  bf8 a0, a1, b0, b1;
#pragma unroll
  for (int e = 0; e < 16; ++e) {
    const float f = tile[kh + e][n];
    const short s1 = f2bf(f);
    const short s2 = f2bf(f - bf2f(s1));
    if (e < 8) { a0[e] = s1; b0[e] = s2; }
    else       { a1[e - 8] = s1; b1[e - 8] = s2; }
  }
  const size_t o = (size_t)(nb + n) * K + kb + kh;
  const size_t ls = (size_t)N * K;
  *reinterpret_cast<bf8*>(out + o) = a0;
  *reinterpret_cast<bf8*>(out + o + 8) = a1;
  *reinterpret_cast<bf8*>(out + o + ls) = b0;
  *reinterpret_cast<bf8*>(out + o + ls + 8) = b1;
}

// 3-level variant (for Wqkv): W[K][N] -> out[lev][N][K], lev stride N*K
__global__ __launch_bounds__(256) void transpose_split3(
    const float* __restrict__ W, short* __restrict__ out, int K, int N) {
  __shared__ float tile[32][129];
  const int t = threadIdx.x;
  const int nb = blockIdx.x * 128, kb = blockIdx.y * 32;
#pragma unroll
  for (int c = 0; c < 4; ++c) {
    const int flat = c * 256 + t;
    const int r = flat >> 5, nq = (flat & 31) * 4;
    const float4 g = *reinterpret_cast<const float4*>(&W[(size_t)(kb + r) * N + nb + nq]);
    tile[r][nq] = g.x; tile[r][nq + 1] = g.y;
    tile[r][nq + 2] = g.z; tile[r][nq + 3] = g.w;
  }
  __syncthreads();
  const int n = t >> 1, kh = (t & 1) * 16;
  bf8 a0, a1, b0, b1, c0, c1;
#pragma unroll
  for (int e = 0; e < 16; ++e) {
    const float f = tile[kh + e][n];
    const short s1 = f2bf(f);  const float r1 = f - bf2f(s1);
    const short s2 = f2bf(r1);
    const short s3 = f2bf(r1 - bf2f(s2));
    if (e < 8) { a0[e] = s1; b0[e] = s2; c0[e] = s3; }
    else       { a1[e - 8] = s1; b1[e - 8] = s2; c1[e - 8] = s3; }
  }
  const size_t o = (size_t)(nb + n) * K + kb + kh;
  const size_t ls = (size_t)N * K;
  *reinterpret_cast<bf8*>(out + o) = a0;
  *reinterpret_cast<bf8*>(out + o + 8) = a1;
  *reinterpret_cast<bf8*>(out + o + ls) = b0;
  *reinterpret_cast<bf8*>(out + o + ls + 8) = b1;
  *reinterpret_cast<bf8*>(out + o + 2 * ls) = c0;
  *reinterpret_cast<bf8*>(out + o + 2 * ls + 8) = c1;
}

// prep: X[8192][512] f32 -> XS[3][8192][512] bf16 (3-level split, row-major)
__global__ __launch_bounds__(256) void xsplit3(
    const float* __restrict__ X, short* __restrict__ XS) {
  const int i = (blockIdx.x * 256 + threadIdx.x) * 8;
  const float4 g0 = *reinterpret_cast<const float4*>(X + i);
  const float4 g1 = *reinterpret_cast<const float4*>(X + i + 4);
  const float v[8] = {g0.x, g0.y, g0.z, g0.w, g1.x, g1.y, g1.z, g1.w};
  bf8 s1v, s2v, s3v;
#pragma unroll
  for (int e = 0; e < 8; ++e) {
    const short s1 = f2bf(v[e]);  const float r1 = v[e] - bf2f(s1);
    const short s2 = f2bf(r1);
    const short s3 = f2bf(r1 - bf2f(s2));
    s1v[e] = s1; s2v[e] = s2; s3v[e] = s3;
  }
  *reinterpret_cast<bf8*>(XS + i)           = s1v;
  *reinterpret_cast<bf8*>(XS + i + 4194304) = s2v;
  *reinterpret_cast<bf8*>(XS + i + 8388608) = s3v;
}

// ---------------------------------------------------------------- K1: qkv GEMM
// Fallback path: f32 VALU (R4-proven numerics).
__global__ __launch_bounds__(256) void qkv_gemm(
    const float* __restrict__ X, const float* __restrict__ W,
    float* __restrict__ Qf32, short* __restrict__ KF, short* __restrict__ VF) {
  __shared__ float As[16][132];
  __shared__ float Bs[16][132];
  const int t = threadIdx.x;
  const int n0 = blockIdx.x * 128;
  const int m0 = blockIdx.y * 128;
  const int ti = t >> 4, tj = t & 15;
  float acc[8][8] = {};
  for (int kt = 0; kt < 512; kt += 16) {
#pragma unroll
    for (int e = 0; e < 2; ++e) {
      int idx = e * 256 + t;
      int m = idx >> 2, kq = (idx & 3) << 2;
      const float4 g = *reinterpret_cast<const float4*>(
          &X[(size_t)(m0 + m) * 512 + kt + kq]);
      As[kq + 0][m] = g.x; As[kq + 1][m] = g.y;
      As[kq + 2][m] = g.z; As[kq + 3][m] = g.w;
    }
#pragma unroll
    for (int e = 0; e < 2; ++e) {
      int idx = e * 256 + t;
      int kk = idx >> 5, n4 = (idx & 31) << 2;
      *reinterpret_cast<float4*>(&Bs[kk][n4]) =
          *reinterpret_cast<const float4*>(&W[(size_t)(kt + kk) * 1536 + n0 + n4]);
    }
    __syncthreads();
#pragma unroll
    for (int kk = 0; kk < 16; ++kk) {
      const float4 A0 = *reinterpret_cast<const float4*>(&As[kk][ti * 8]);
      const float4 A1 = *reinterpret_cast<const float4*>(&As[kk][ti * 8 + 4]);
      const float4 B0 = *reinterpret_cast<const float4*>(&Bs[kk][tj * 8]);
      const float4 B1 = *reinterpret_cast<const float4*>(&Bs[kk][tj * 8 + 4]);
      const float a[8] = {A0.x, A0.y, A0.z, A0.w, A1.x, A1.y, A1.z, A1.w};
      const float b[8] = {B0.x, B0.y, B0.z, B0.w, B1.x, B1.y, B1.z, B1.w};
#pragma unroll
      for (int ii = 0; ii < 8; ++ii)
#pragma unroll
        for (int jj = 0; jj < 8; ++jj)
          acc[ii][jj] = fmaf(a[ii], b[jj], acc[ii][jj]);
    }
    __syncthreads();
  }
  const int part = n0 >> 9;     // 0=Q 1=K 2=V
  if (part == 0) {
#pragma unroll
    for (int ii = 0; ii < 8; ++ii) {
      const int r = m0 + ti * 8 + ii;
      const int bb = r >> 11, tt = r & 2047;
#pragma unroll
      for (int jj = 0; jj < 8; ++jj) {
        const int c = (n0 & 511) + tj * 8 + jj;
        const int h = c >> 6, d = c & 63;
        Qf32[(size_t)(bb * 8 + h) * 131072 + (size_t)tt * 64 + d] =
            acc[ii][jj] * 0.125f;
      }
    }
  } else if (part == 1) {
    const int cc0 = (n0 & 511) + tj * 8;
    const int h = cc0 >> 6, d0 = cc0 & 63;
    const int kk = d0 >> 5, lg = (d0 & 31) >> 3;   // j = d&7 == jj
#pragma unroll
    for (int ii = 0; ii < 8; ++ii) {
      const int r = m0 + ti * 8 + ii;
      const int bb = r >> 11, tt = r & 2047;
      const size_t base = (size_t)(bb * 8 + h) * 393216 +
                          (size_t)(tt >> 4) * 3072 + kk * 512 +
                          ((tt & 15) + 16 * lg) * 8;
      bf8 v1, v2, v3;
#pragma unroll
      for (int jj = 0; jj < 8; ++jj) {
        const float f = acc[ii][jj];
        const short s1 = f2bf(f);  const float r1 = f - bf2f(s1);
        const short s2 = f2bf(r1);
        const short s3 = f2bf(r1 - bf2f(s2));
        v1[jj] = s1; v2[jj] = s2; v3[jj] = s3;
      }
      *reinterpret_cast<bf8*>(KF + base)        = v1;
      *reinterpret_cast<bf8*>(KF + base + 1024) = v2;
      *reinterpret_cast<bf8*>(KF + base + 2048) = v3;
    }
  } else {
    const int t0r = m0 + ti * 8;                 // 8-aligned -> j = s&7 == ii
    const int bb = t0r >> 11, tt0 = t0r & 2047;
    const int cc = tt0 >> 5, lgs = (tt0 & 31) >> 3;
#pragma unroll
    for (int jj = 0; jj < 8; ++jj) {
      const int c = (n0 & 511) + tj * 8 + jj;
      const int h = c >> 6, dd = c & 63;
      bf8 pv;
#pragma unroll
      for (int ii = 0; ii < 8; ++ii) pv[ii] = f2bf(acc[ii][jj]);
      *reinterpret_cast<bf8*>(VF + (size_t)(bb * 8 + h) * 131072 +
                              cc * 2048 + (dd >> 4) * 512 +
                              ((dd & 15) + 16 * lgs) * 8) = pv;
    }
  }
}

// ---------------------------------------- K1': qkv GEMM via MFMA (main path)
// A = XS [3][8192][512], B = WqS [3][1536][512], 6-term ladder (3 for V part).
// Accs round-trip through LDS scratch so the proven (ti,tj) epilogue is reused.
__global__ __launch_bounds__(256) void qkv_mfma(
    const short* __restrict__ XS, const short* __restrict__ WqS,
    float* __restrict__ Qf32, short* __restrict__ KF, short* __restrict__ VF) {
  extern __shared__ char sm_[];
  short* As = (short*)sm_;                 // [3][128][40] bf16
  short* Bs = (short*)(sm_ + 30720);       // [3][128][40] bf16
  float* SC = (float*)sm_;                 // [128][132] f32 (after k-loop)
  const int t = threadIdx.x;
  const int w = t >> 6, lane = t & 63;
  const int lq = lane & 15, lg = lane >> 4;
  const int wr = w >> 1, wc = w & 1;
  const int n0 = blockIdx.x * 128, m0 = blockIdx.y * 128;
  const int part = n0 >> 9;                // 0=Q 1=K 2=V
  const int LV = (part == 2) ? 2 : 3;      // levels staged / ladder depth
  f32x4 acc[4][4];
#pragma unroll
  for (int i = 0; i < 4; ++i)
#pragma unroll
    for (int j2 = 0; j2 < 4; ++j2) acc[i][j2] = (f32x4){0.f, 0.f, 0.f, 0.f};
  const int sr = t >> 1, sh = (t & 1) * 16;
  for (int k0 = 0; k0 < 512; k0 += 32) {
    for (int lev = 0; lev < LV; ++lev) {
      const size_t xa = (size_t)lev * 4194304 + (size_t)(m0 + sr) * 512 + k0 + sh;
      *reinterpret_cast<bf8*>(&As[(lev * 128 + sr) * 40 + sh])     =
          *reinterpret_cast<const bf8*>(XS + xa);
      *reinterpret_cast<bf8*>(&As[(lev * 128 + sr) * 40 + sh + 8]) =
          *reinterpret_cast<const bf8*>(XS + xa + 8);
      const size_t wa = (size_t)lev * 786432 + (size_t)(n0 + sr) * 512 + k0 + sh;
      *reinterpret_cast<bf8*>(&Bs[(lev * 128 + sr) * 40 + sh])     =
          *reinterpret_cast<const bf8*>(WqS + wa);
      *reinterpret_cast<bf8*>(&Bs[(lev * 128 + sr) * 40 + sh + 8]) =
          *reinterpret_cast<const bf8*>(WqS + wa + 8);
    }
    __syncthreads();
    bf8 bfr[4][3];
#pragma unroll
    for (int i = 0; i < 4; ++i)
      for (int lev = 0; lev < LV; ++lev)
        bfr[i][lev] = *reinterpret_cast<const bf8*>(
            &Bs[(lev * 128 + wc * 64 + i * 16 + lq) * 40 + lg * 8]);
#pragma unroll
    for (int mi = 0; mi < 4; ++mi) {
      bf8 af[3];
      for (int lev = 0; lev < LV; ++lev)
        af[lev] = *reinterpret_cast<const bf8*>(
            &As[(lev * 128 + wr * 64 + mi * 16 + lq) * 40 + lg * 8]);
#pragma unroll
      for (int ni = 0; ni < 4; ++ni) {
        MFMA16(af[0], bfr[ni][0], acc[mi][ni]);       // 1
        MFMA16(af[0], bfr[ni][1], acc[mi][ni]);       // 2^-8
        MFMA16(af[1], bfr[ni][0], acc[mi][ni]);       // 2^-8
        if (LV == 3) {
          MFMA16(af[1], bfr[ni][1], acc[mi][ni]);     // 2^-16
          MFMA16(af[0], bfr[ni][2], acc[mi][ni]);     // 2^-16
          MFMA16(af[2], bfr[ni][0], acc[mi][ni]);     // 2^-16
        }
      }
    }
    __syncthreads();
  }
  // dump accs to scratch in (m,n) order
#pragma unroll
  for (int mi = 0; mi < 4; ++mi)
#pragma unroll
    for (int ni = 0; ni < 4; ++ni)
#pragma unroll
      for (int r = 0; r < 4; ++r)
        SC[(wr * 64 + mi * 16 + lg * 4 + r) * 132 + wc * 64 + ni * 16 + lq] =
            acc[mi][ni][r];
  __syncthreads();
  // epilogue: verbatim qkv_gemm scatter, accL re-read in (ti,tj) 8x8 order
  const int ti = t >> 4, tj = t & 15;
  float accL[8][8];
#pragma unroll
  for (int ii = 0; ii < 8; ++ii) {
    const float4 c0 = *reinterpret_cast<const float4*>(&SC[(ti * 8 + ii) * 132 + tj * 8]);
    const float4 c1 = *reinterpret_cast<const float4*>(&SC[(ti * 8 + ii) * 132 + tj * 8 + 4]);
    accL[ii][0] = c0.x; accL[ii][1] = c0.y; accL[ii][2] = c0.z; accL[ii][3] = c0.w;
    accL[ii][4] = c1.x; accL[ii][5] = c1.y; accL[ii][6] = c1.z; accL[ii][7] = c1.w;
  }
  if (part == 0) {
#pragma unroll
    for (int ii = 0; ii < 8; ++ii) {
      const int r = m0 + ti * 8 + ii;
      const int bb = r >> 11, tt = r & 2047;
#pragma unroll
      for (int jj = 0; jj < 8; ++jj) {
        const int c = (n0 & 511) + tj * 8 + jj;
        const int h = c >> 6, d = c & 63;
        Qf32[(size_t)(bb * 8 + h) * 131072 + (size_t)tt * 64 + d] =
            accL[ii][jj] * 0.125f;
      }
    }
  } else if (part == 1) {
    const int cc0 = (n0 & 511) + tj * 8;
    const int h = cc0 >> 6, d0 = cc0 & 63;
    const int kk = d0 >> 5, lg2 = (d0 & 31) >> 3;   // j = d&7 == jj
#pragma unroll
    for (int ii = 0; ii < 8; ++ii) {
      const int r = m0 + ti * 8 + ii;
      const int bb = r >> 11, tt = r & 2047;
      const size_t base = (size_t)(bb * 8 + h) * 393216 +
                          (size_t)(tt >> 4) * 3072 + kk * 512 +
                          ((tt & 15) + 16 * lg2) * 8;
      bf8 v1, v2, v3;
#pragma unroll
      for (int jj = 0; jj < 8; ++jj) {
        const float f = accL[ii][jj];
        const short s1 = f2bf(f);  const float r1 = f - bf2f(s1);
        const short s2 = f2bf(r1);
        const short s3 = f2bf(r1 - bf2f(s2));
        v1[jj] = s1; v2[jj] = s2; v3[jj] = s3;
      }
      *reinterpret_cast<bf8*>(KF + base)        = v1;
      *reinterpret_cast<bf8*>(KF + base + 1024) = v2;
      *reinterpret_cast<bf8*>(KF + base + 2048) = v3;
    }
  } else {
    const int t0r = m0 + ti * 8;                 // 8-aligned -> j = s&7 == ii
    const int bb = t0r >> 11, tt0 = t0r & 2047;
    const int cc = tt0 >> 5, lgs = (tt0 & 31) >> 3;
#pragma unroll
    for (int jj = 0; jj < 8; ++jj) {
      const int c = (n0 & 511) + tj * 8 + jj;
      const int h = c >> 6, dd = c & 63;
      bf8 pv;
#pragma unroll
      for (int ii = 0; ii < 8; ++ii) pv[ii] = f2bf(accL[ii][jj]);
      *reinterpret_cast<bf8*>(VF + (size_t)(bb * 8 + h) * 131072 +
                              cc * 2048 + (dd >> 4) * 512 +
                              ((dd & 15) + 16 * lgs) * 8) = pv;
    }
  }
}

// ------------------------------------------------------------- K3: out proj GEMM
__global__ __launch_bounds__(256) void out_mfma(
    const short* __restrict__ HOS, const short* __restrict__ WoS,
    float* __restrict__ OUT) {
  __shared__ short As[2][128][40];
  __shared__ short Bs[2][128][40];
  const int t = threadIdx.x;
  const int w = t >> 6, lane = t & 63;
  const int lq = lane & 15, lg = lane >> 4;
  const int wr = w >> 1, wc = w & 1;
  const int n0 = blockIdx.x * 128, m0 = blockIdx.y * 128;
  f32x4 acc[4][4];
#pragma unroll
  for (int i = 0; i < 4; ++i)
#pragma unroll
    for (int j2 = 0; j2 < 4; ++j2) acc[i][j2] = (f32x4){0.f, 0.f, 0.f, 0.f};
  const int sm = t >> 1, sh = (t & 1) * 16;
  for (int k0 = 0; k0 < 512; k0 += 32) {
#pragma unroll
    for (int lev = 0; lev < 2; ++lev) {
      const size_t xa = (size_t)lev * 4194304 + (size_t)(m0 + sm) * 512 + k0 + sh;
      *reinterpret_cast<bf8*>(&As[lev][sm][sh])     = *reinterpret_cast<const bf8*>(HOS + xa);
      *reinterpret_cast<bf8*>(&As[lev][sm][sh + 8]) = *reinterpret_cast<const bf8*>(HOS + xa + 8);
      const size_t wa = (size_t)lev * 262144 + (size_t)(n0 + sm) * 512 + k0 + sh;
      *reinterpret_cast<bf8*>(&Bs[lev][sm][sh])     = *reinterpret_cast<const bf8*>(WoS + wa);
      *reinterpret_cast<bf8*>(&Bs[lev][sm][sh + 8]) = *reinterpret_cast<const bf8*>(WoS + wa + 8);
    }
    __syncthreads();
    bf8 af[4][2], bfr[4][2];
#pragma unroll
    for (int i = 0; i < 4; ++i)
#pragma unroll
      for (int lev = 0; lev < 2; ++lev) {
        af[i][lev]  = *reinterpret_cast<const bf8*>(&As[lev][wr * 64 + i * 16 + lq][lg * 8]);
        bfr[i][lev] = *reinterpret_cast<const bf8*>(&Bs[lev][wc * 64 + i * 16 + lq][lg * 8]);
      }
#pragma unroll
    for (int mi = 0; mi < 4; ++mi)
#pragma unroll
      for (int ni = 0; ni < 4; ++ni) {
        MFMA16(af[mi][0], bfr[ni][0], acc[mi][ni]);
        MFMA16(af[mi][0], bfr[ni][1], acc[mi][ni]);
        MFMA16(af[mi][1], bfr[ni][0], acc[mi][ni]);
      }
    __syncthreads();
  }
#pragma unroll
  for (int mi = 0; mi < 4; ++mi)
#pragma unroll
    for (int r = 0; r < 4; ++r) {
      const int m = m0 + wr * 64 + mi * 16 + lg * 4 + r;
#pragma unroll
      for (int ni = 0; ni < 4; ++ni)
        OUT[(size_t)m * 512 + n0 + wc * 64 + ni * 16 + lq] = acc[mi][ni][r];
    }
}

// ---------------------------------------------------------------- K2: attention
// 512 threads = 8 waves; 8 q-rows/block; 64 KB LDS -> 2 blocks/CU.
// Lanes lq>=8 duplicate rows 0-7 (row = lq&7): same-address/same-value LDS
// writes in P1, duplicate (discarded) MFMA rows in P3.
__global__ __launch_bounds__(512, 4) void attn_mfma(
    const float* __restrict__ Qf32, const short* __restrict__ KF,
    const short* __restrict__ VF, const float* __restrict__ alpha,
    short* __restrict__ HOS) {
  extern __shared__ char lds[];
  const int tid = threadIdx.x;
  const int w = tid >> 6, lane = tid & 63;      // w in [0,8)
  const int lq = lane & 15, lg = lane >> 4;
  const int row = lq & 7;

  // XCD swizzle: 8192 blocks, 1024/XCD = 4 bh x 256 qb
  const int flat = blockIdx.x + (int)gridDim.x * blockIdx.y;
  const int xcd = flat & 7, idx = flat >> 3;
  const int bh = xcd * 4 + (idx >> 8);
  const int qb = idx & 255;
  const int b = bh >> 3, h = bh & 7;
  const int q0 = qb * 8;

  const float gate = 1.0f / (1.0f + __expf(-alpha[h]));
  const int key = row;                           // row's swizzle key (row < 8)

  // Q fragments: load f32 row q0+row, split 3-level in-register
  bf8 qf[3][2];
  {
    const float* qp = Qf32 + (size_t)bh * 131072 + (size_t)(q0 + row) * 64 + lg * 8;
#pragma unroll
    for (int kk = 0; kk < 2; ++kk) {
      const float4 g0 = *reinterpret_cast<const float4*>(qp + kk * 32);
      const float4 g1 = *reinterpret_cast<const float4*>(qp + kk * 32 + 4);
      const float v[8] = {g0.x, g0.y, g0.z, g0.w, g1.x, g1.y, g1.z, g1.w};
#pragma unroll
      for (int e = 0; e < 8; ++e) {
        const short s1 = f2bf(v[e]);  const float r1 = v[e] - bf2f(s1);
        const short s2 = f2bf(r1);
        const short s3 = f2bf(r1 - bf2f(s2));
        qf[0][kk][e] = s1; qf[1][kk][e] = s2; qf[2][kk][e] = s3;
      }
    }
  }

  auto ldk = [&](int t, bf8 (&dst)[3][2]) {
    const short* p = KF + (size_t)(bh * 128 + t) * 3072 + lane * 8;
    dst[0][0] = *reinterpret_cast<const bf8*>(p);
    dst[0][1] = *reinterpret_cast<const bf8*>(p + 512);
    dst[1][0] = *reinterpret_cast<const bf8*>(p + 1024);
    dst[1][1] = *reinterpret_cast<const bf8*>(p + 1536);
    dst[2][0] = *reinterpret_cast<const bf8*>(p + 2048);
    dst[2][1] = *reinterpret_cast<const bf8*>(p + 2560);
  };
  auto qk = [&](bf8 (&kf)[3][2], int t) {
    f32x4 c0 = {0.f,0.f,0.f,0.f}, c1 = {0.f,0.f,0.f,0.f}, c2 = {0.f,0.f,0.f,0.f};
#pragma unroll
    for (int kk = 0; kk < 2; ++kk) {
      MFMA16(kf[0][kk], qf[0][kk], c0);   // 1
      MFMA16(kf[0][kk], qf[1][kk], c1);   // 2^-8
      MFMA16(kf[1][kk], qf[0][kk], c1);   // 2^-8
      MFMA16(kf[1][kk], qf[1][kk], c2);   // 2^-16
      MFMA16(kf[0][kk], qf[2][kk], c2);   // 2^-16
      MFMA16(kf[2][kk], qf[0][kk], c2);   // 2^-16
    }
    const f32x4 c = (c0 + c1) + c2;
    // lanes lq>=8 write the same address+value as their lq-8 twin (benign)
    *reinterpret_cast<f32x4*>(
        lds + row * 8192 + ((((t << 2) + lg) ^ key) << 4)) = c;
  };

  // ---- P1: logits (double-buffered, 16 tiles/wave)
  {
    bf8 ka[3][2], kb[3][2];
    ldk(w, ka);
#pragma unroll
    for (int j = 0; j < 16; j += 2) {
      const int t0 = w + 8 * j;
      ldk(t0 + 8, kb);
      qk(ka, t0);
      if (j + 2 < 16) ldk(t0 + 16, ka);
      qk(kb, t0 + 8);
    }
  }
  __syncthreads();

  // V prefetch for P3 chunk w (latency hidden under P2)
  bf8 va[4], vb[4];
  auto ldv = [&](int cc, bf8 (&dst)[4]) {
    const short* p = VF + (size_t)(bh * 64 + cc) * 2048 + lane * 8;
    dst[0] = *reinterpret_cast<const bf8*>(p);
    dst[1] = *reinterpret_cast<const bf8*>(p + 512);
    dst[2] = *reinterpret_cast<const bf8*>(p + 1024);
    dst[3] = *reinterpret_cast<const bf8*>(p + 1536);
  };
  ldv(w, va);

  // ---- P2: wave w owns row q=w. Exact top-64 threshold; counts via
  // ballot+popcount (SALU) instead of per-lane add + shfl reduce chains.
  {
    const int q = w;
    const int rkey = q & 7;
    const char* rowb = lds + q * 8192;
    unsigned uv[32];
    float lm = -3.402823466e+38f;
#pragma unroll
    for (int jj = 0; jj < 8; ++jj) {
      const f32x4 v = *reinterpret_cast<const f32x4*>(rowb + ((lane + 64 * jj) << 4));
#pragma unroll
      for (int e = 0; e < 4; ++e) {
        const float a = v[e];
        lm = fmaxf(lm, a);
        const unsigned fb = __float_as_uint(a);
        uv[jj * 4 + e] = (fb & 0x80000000u) ? ~fb : (fb | 0x80000000u);
      }
    }
    // m = global max; g0 = min of per-lane maxima -> cnt(>=g0) >= 64,
    // so the 64th-largest lies in [g0, m].
    float m = lm, g0 = lm;
#pragma unroll
    for (int off = 32; off; off >>= 1) m = fmaxf(m, __shfl_xor(m, off));
#pragma unroll
    for (int off = 32; off; off >>= 1) g0 = fminf(g0, __shfl_xor(g0, off));
    float ev[32]; float dsum = 0.f;
#pragma unroll
    for (int j = 0; j < 32; ++j) {
      const unsigned u = uv[j];
      const float a = __uint_as_float((u & 0x80000000u) ? (u & 0x7fffffffu) : ~u);
      ev[j] = __expf(a - m);
      dsum += ev[j];
    }
#pragma unroll
    for (int off = 32; off; off >>= 1) dsum += __shfl_xor(dsum, off);
    const unsigned um_ = __float_as_uint(m);
    const unsigned ug_ = __float_as_uint(g0);
    // scalarize bounds: loop control + candidates live entirely in SGPRs
    unsigned lo = __builtin_amdgcn_readfirstlane(
        (ug_ & 0x80000000u) ? ~ug_ : (ug_ | 0x80000000u));
    unsigned hi = __builtin_amdgcn_readfirstlane(
        (um_ & 0x80000000u) ? ~um_ : (um_ | 0x80000000u));
    // invariant: cnt(>= lo) >= 64. Find max T with cnt(>= T) >= 64.
    while (lo < hi) {
      const unsigned mid = lo + ((hi - lo + 1) >> 1);   // mid in (lo, hi]
      int cnt = 0;
#pragma unroll
      for (int j = 0; j < 32; ++j)
        cnt += (int)__popcll(__ballot(uv[j] >= mid));
      if (cnt >= 64) {
        lo = mid;
        if (cnt == 64) break;
      } else {
        hi = mid - 1;
      }
    }
    const unsigned thr = lo;
    float ssum = 0.f;
#pragma unroll
    for (int j = 0; j < 32; ++j) ssum += (uv[j] >= thr) ? ev[j] : 0.f;
#pragma unroll
    for (int off = 32; off; off >>= 1) ssum += __shfl_xor(ssum, off);
    const float dinv = gate / dsum;
    const float sinv = (1.0f - gate) / ssum;
#pragma unroll
    for (int jj = 0; jj < 8; ++jj) {
      const int p = lane + 64 * jj;
      const int f = p ^ rkey;
      const float w0 = ev[jj*4+0] * (dinv + ((uv[jj*4+0] >= thr) ? sinv : 0.f));
      const float w1 = ev[jj*4+1] * (dinv + ((uv[jj*4+1] >= thr) ? sinv : 0.f));
      const float w2 = ev[jj*4+2] * (dinv + ((uv[jj*4+2] >= thr) ? sinv : 0.f));
      const float w3 = ev[jj*4+3] * (dinv + ((uv[jj*4+3] >= thr) ? sinv : 0.f));
      uint2 pk;
      pk.x = (unsigned)(unsigned short)f2bf(w0) |
             ((unsigned)(unsigned short)f2bf(w1) << 16);
      pk.y = (unsigned)(unsigned short)f2bf(w2) |
             ((unsigned)(unsigned short)f2bf(w3) << 16);
      *reinterpret_cast<uint2*>(
          lds + q * 8192 + ((((f >> 1) ^ rkey) << 4) + ((f & 1) << 3))) = pk;
    }
  }
  __syncthreads();

  // ---- P3: PV. wave w does s-chunks cc = w + 8j (8 chunks of 32 s), 4 d-tiles.
  f32x4 o0 = {0.f,0.f,0.f,0.f}, o1 = {0.f,0.f,0.f,0.f};
  f32x4 o2 = {0.f,0.f,0.f,0.f}, o3 = {0.f,0.f,0.f,0.f};
  {
    auto pv = [&](bf8 (&vv)[4], int cc) {
      const bf8 pa = *reinterpret_cast<const bf8*>(
          lds + row * 8192 + ((((cc << 2) + lg) ^ key) << 4));
      MFMA16(pa, vv[0], o0);
      MFMA16(pa, vv[1], o1);
      MFMA16(pa, vv[2], o2);
      MFMA16(pa, vv[3], o3);
    };
#pragma unroll
    for (int j = 0; j < 8; j += 2) {
      const int cc = w + 8 * j;
      ldv(cc + 8, vb);
      pv(va, cc);
      if (j + 2 < 8) ldv(cc + 16, va);
      pv(vb, cc + 8);
    }
  }
  // park partials: tile = w*4+dt in [0,32): row tile&7, slot tile>>3
  {
    const f32x4 oo[4] = {o0, o1, o2, o3};
#pragma unroll
    for (int dt = 0; dt < 4; ++dt) {
      const int tile = w * 4 + dt;
      char* pb = lds + (tile & 7) * 8192 + 4096 + ((tile >> 3) << 10);
#pragma unroll
      for (int r = 0; r < 4; ++r)
        *reinterpret_cast<float*>(pb + (((lg * 4 + r) * 16 + lq) << 2)) = oo[dt][r];
    }
  }
  __syncthreads();
  // reduce 8 wave-partials, write HOS (2-level bf16). 512 thr = 8 q x 64 d.
  {
    const int q = tid >> 6, d = tid & 63;
    const int dt = d >> 4;
    float s = 0.f;
#pragma unroll
    for (int ww = 0; ww < 8; ++ww) {
      const int tile = ww * 4 + dt;
      s += *reinterpret_cast<const float*>(
          lds + (tile & 7) * 8192 + 4096 + ((tile >> 3) << 10) +
          ((q * 16 + (d & 15)) << 2));
    }
    const size_t o = (size_t)(b * TSEQ + q0 + q) * 512 + h * 64 + d;
    const short s1 = f2bf(s);
    HOS[o] = s1;
    HOS[o + 4194304] = f2bf(s - bf2f(s1));
  }
}

// ------------------------------------------------------------------- launcher
extern "C" void kernel_launch(void* const* d_in, const int* in_sizes, int n_in,
                              void* d_out, int out_size, void* d_ws, size_t ws_size,
                              hipStream_t stream) {
  const float* x     = (const float*)d_in[0];
  const float* Wqkv  = (const float*)d_in[1];
  const float* Wout  = (const float*)d_in[2];
  const float* alpha = (const float*)d_in[3];
  float* out = (float*)d_out;

  float* Qf32 = (float*)d_ws;
  short* S16  = (short*)d_ws;
  short* KF   = S16 + 8388608;
  short* VF   = S16 + 20971520;
  short* HOS  = S16 + 25165824;
  short* WoS  = S16 + 33554432;
  short* WqS  = S16 + 34078720;   // 3 x 1536 x 512
  short* XSp  = S16 + 36438016;   // 3 x 8192 x 512

  const int attn_lds = 65536;
  (void)hipFuncSetAttribute((const void*)attn_mfma,
                            hipFuncAttributeMaxDynamicSharedMemorySize, attn_lds);

  transpose_split<<<dim3(4, 16), 256, 0, stream>>>(Wout, WoS, 512, 512);

  const bool big = ws_size >= (size_t)98041856;
  if (big) {
    transpose_split3<<<dim3(12, 16), 256, 0, stream>>>(Wqkv, WqS, 512, 1536);
    xsplit3<<<2048, 256, 0, stream>>>(x, XSp);
    const int qkv_lds = 67584;
    (void)hipFuncSetAttribute((const void*)qkv_mfma,
                              hipFuncAttributeMaxDynamicSharedMemorySize, qkv_lds);
    qkv_mfma<<<dim3(12, 64), 256, qkv_lds, stream>>>(XSp, WqS, Qf32, KF, VF);
  } else {
    qkv_gemm<<<dim3(12, 64), 256, 0, stream>>>(x, Wqkv, Qf32, KF, VF);
  }
  attn_mfma<<<dim3(256, 32), 512, attn_lds, stream>>>(Qf32, KF, VF, alpha, HOS);
  out_mfma<<<dim3(4, 64), 256, 0, stream>>>(HOS, WoS, out);
}

// Round 3
// 500.421 us; speedup vs baseline: 3.0549x; 3.0549x over previous
//
#include <hip/hip_runtime.h>
#include <cstdint>
#include <cstddef>

// AdaptiveSparseSelfAttention — round 11: fix R10's rule-#20 violation.
// qkv_mfma's `LV` was runtime (blockIdx-derived) -> af[]/bfr[] lev-indexed by a
// runtime loop bound -> scratch allocation -> every MFMA operand through
// scratch (VGPR 84, MfmaUtil 2%, ~1 GB spill traffic, 1170 us). Now LV=3 is
// hardcoded for ALL parts (V gets the 6-term ladder too — strictly more
// accurate than R10's 3-term), every lev loop has a literal bound + unroll,
// all indexing compile-time. attn_mfma / out_mfma / epilogues byte-identical.
//
// ws layout (98,041,856 B total when big path active):
//   Qf32 f32  [32][2048][64]                4,194,304 f  @ short 0
//   KF   bf16 [32][128 kt][3][2][64][8]    12,582,912 s  @ short 8,388,608
//   VF   bf16 [32][64 cc][4 dt][64][8]      4,194,304 s  @ short 20,971,520
//   HOS  bf16 [2 lev][8192][512]            8,388,608 s  @ short 25,165,824
//   WoS  bf16 [2 lev][512][512]               524,288 s  @ short 33,554,432
//   WqS  bf16 [3 lev][1536][512]            2,359,296 s  @ short 34,078,720
//   XS   bf16 [3 lev][8192][512]           12,582,912 s  @ short 36,438,016

#define TSEQ 2048

typedef __attribute__((ext_vector_type(8))) short bf8;
typedef __attribute__((ext_vector_type(4))) float f32x4;

#define MFMA16(A, B, C) \
  C = __builtin_amdgcn_mfma_f32_16x16x32_bf16(A, B, C, 0, 0, 0)

static __device__ __forceinline__ short f2bf(float f) {
  unsigned u = __float_as_uint(f);
  u += 0x7FFFu + ((u >> 16) & 1u);
  return (short)(u >> 16);
}
static __device__ __forceinline__ float bf2f(short s) {
  return __uint_as_float(((unsigned)(unsigned short)s) << 16);
}

// ---------------------------------------- prep: transpose + split weight matrix
// W[K][N] -> out[lev][N][K], lev stride N*K (2 levels, for Wout)
__global__ __launch_bounds__(256) void transpose_split(
    const float* __restrict__ W, short* __restrict__ out, int K, int N) {
  __shared__ float tile[32][129];
  const int t = threadIdx.x;
  const int nb = blockIdx.x * 128, kb = blockIdx.y * 32;
#pragma unroll
  for (int c = 0; c < 4; ++c) {
    const int flat = c * 256 + t;
    const int r = flat >> 5, nq = (flat & 31) * 4;
    const float4 g = *reinterpret_cast<const float4*>(&W[(size_t)(kb + r) * N + nb + nq]);
    tile[r][nq] = g.x; tile[r][nq + 1] = g.y;
    tile[r][nq + 2] = g.z; tile[r][nq + 3] = g.w;
  }
  __syncthreads();
  const int n = t >> 1, kh = (t & 1) * 16;
  bf8 a0, a1, b0, b1;
#pragma unroll
  for (int e = 0; e < 16; ++e) {
    const float f = tile[kh + e][n];
    const short s1 = f2bf(f);
    const short s2 = f2bf(f - bf2f(s1));
    if (e < 8) { a0[e] = s1; b0[e] = s2; }
    else       { a1[e - 8] = s1; b1[e - 8] = s2; }
  }
  const size_t o = (size_t)(nb + n) * K + kb + kh;
  const size_t ls = (size_t)N * K;
  *reinterpret_cast<bf8*>(out + o) = a0;
  *reinterpret_cast<bf8*>(out + o + 8) = a1;
  *reinterpret_cast<bf8*>(out + o + ls) = b0;
  *reinterpret_cast<bf8*>(out + o + ls + 8) = b1;
}

// 3-level variant (for Wqkv): W[K][N] -> out[lev][N][K], lev stride N*K
__global__ __launch_bounds__(256) void transpose_split3(
    const float* __restrict__ W, short* __restrict__ out, int K, int N) {
  __shared__ float tile[32][129];
  const int t = threadIdx.x;
  const int nb = blockIdx.x * 128, kb = blockIdx.y * 32;
#pragma unroll
  for (int c = 0; c < 4; ++c) {
    const int flat = c * 256 + t;
    const int r = flat >> 5, nq = (flat & 31) * 4;
    const float4 g = *reinterpret_cast<const float4*>(&W[(size_t)(kb + r) * N + nb + nq]);
    tile[r][nq] = g.x; tile[r][nq + 1] = g.y;
    tile[r][nq + 2] = g.z; tile[r][nq + 3] = g.w;
  }
  __syncthreads();
  const int n = t >> 1, kh = (t & 1) * 16;
  bf8 a0, a1, b0, b1, c0, c1;
#pragma unroll
  for (int e = 0; e < 16; ++e) {
    const float f = tile[kh + e][n];
    const short s1 = f2bf(f);  const float r1 = f - bf2f(s1);
    const short s2 = f2bf(r1);
    const short s3 = f2bf(r1 - bf2f(s2));
    if (e < 8) { a0[e] = s1; b0[e] = s2; c0[e] = s3; }
    else       { a1[e - 8] = s1; b1[e - 8] = s2; c1[e - 8] = s3; }
  }
  const size_t o = (size_t)(nb + n) * K + kb + kh;
  const size_t ls = (size_t)N * K;
  *reinterpret_cast<bf8*>(out + o) = a0;
  *reinterpret_cast<bf8*>(out + o + 8) = a1;
  *reinterpret_cast<bf8*>(out + o + ls) = b0;
  *reinterpret_cast<bf8*>(out + o + ls + 8) = b1;
  *reinterpret_cast<bf8*>(out + o + 2 * ls) = c0;
  *reinterpret_cast<bf8*>(out + o + 2 * ls + 8) = c1;
}

// prep: X[8192][512] f32 -> XS[3][8192][512] bf16 (3-level split, row-major)
__global__ __launch_bounds__(256) void xsplit3(
    const float* __restrict__ X, short* __restrict__ XS) {
  const int i = (blockIdx.x * 256 + threadIdx.x) * 8;
  const float4 g0 = *reinterpret_cast<const float4*>(X + i);
  const float4 g1 = *reinterpret_cast<const float4*>(X + i + 4);
  const float v[8] = {g0.x, g0.y, g0.z, g0.w, g1.x, g1.y, g1.z, g1.w};
  bf8 s1v, s2v, s3v;
#pragma unroll
  for (int e = 0; e < 8; ++e) {
    const short s1 = f2bf(v[e]);  const float r1 = v[e] - bf2f(s1);
    const short s2 = f2bf(r1);
    const short s3 = f2bf(r1 - bf2f(s2));
    s1v[e] = s1; s2v[e] = s2; s3v[e] = s3;
  }
  *reinterpret_cast<bf8*>(XS + i)           = s1v;
  *reinterpret_cast<bf8*>(XS + i + 4194304) = s2v;
  *reinterpret_cast<bf8*>(XS + i + 8388608) = s3v;
}

// ---------------------------------------------------------------- K1: qkv GEMM
// Fallback path: f32 VALU (R4-proven numerics).
__global__ __launch_bounds__(256) void qkv_gemm(
    const float* __restrict__ X, const float* __restrict__ W,
    float* __restrict__ Qf32, short* __restrict__ KF, short* __restrict__ VF) {
  __shared__ float As[16][132];
  __shared__ float Bs[16][132];
  const int t = threadIdx.x;
  const int n0 = blockIdx.x * 128;
  const int m0 = blockIdx.y * 128;
  const int ti = t >> 4, tj = t & 15;
  float acc[8][8] = {};
  for (int kt = 0; kt < 512; kt += 16) {
#pragma unroll
    for (int e = 0; e < 2; ++e) {
      int idx = e * 256 + t;
      int m = idx >> 2, kq = (idx & 3) << 2;
      const float4 g = *reinterpret_cast<const float4*>(
          &X[(size_t)(m0 + m) * 512 + kt + kq]);
      As[kq + 0][m] = g.x; As[kq + 1][m] = g.y;
      As[kq + 2][m] = g.z; As[kq + 3][m] = g.w;
    }
#pragma unroll
    for (int e = 0; e < 2; ++e) {
      int idx = e * 256 + t;
      int kk = idx >> 5, n4 = (idx & 31) << 2;
      *reinterpret_cast<float4*>(&Bs[kk][n4]) =
          *reinterpret_cast<const float4*>(&W[(size_t)(kt + kk) * 1536 + n0 + n4]);
    }
    __syncthreads();
#pragma unroll
    for (int kk = 0; kk < 16; ++kk) {
      const float4 A0 = *reinterpret_cast<const float4*>(&As[kk][ti * 8]);
      const float4 A1 = *reinterpret_cast<const float4*>(&As[kk][ti * 8 + 4]);
      const float4 B0 = *reinterpret_cast<const float4*>(&Bs[kk][tj * 8]);
      const float4 B1 = *reinterpret_cast<const float4*>(&Bs[kk][tj * 8 + 4]);
      const float a[8] = {A0.x, A0.y, A0.z, A0.w, A1.x, A1.y, A1.z, A1.w};
      const float b[8] = {B0.x, B0.y, B0.z, B0.w, B1.x, B1.y, B1.z, B1.w};
#pragma unroll
      for (int ii = 0; ii < 8; ++ii)
#pragma unroll
        for (int jj = 0; jj < 8; ++jj)
          acc[ii][jj] = fmaf(a[ii], b[jj], acc[ii][jj]);
    }
    __syncthreads();
  }
  const int part = n0 >> 9;     // 0=Q 1=K 2=V
  if (part == 0) {
#pragma unroll
    for (int ii = 0; ii < 8; ++ii) {
      const int r = m0 + ti * 8 + ii;
      const int bb = r >> 11, tt = r & 2047;
#pragma unroll
      for (int jj = 0; jj < 8; ++jj) {
        const int c = (n0 & 511) + tj * 8 + jj;
        const int h = c >> 6, d = c & 63;
        Qf32[(size_t)(bb * 8 + h) * 131072 + (size_t)tt * 64 + d] =
            acc[ii][jj] * 0.125f;
      }
    }
  } else if (part == 1) {
    const int cc0 = (n0 & 511) + tj * 8;
    const int h = cc0 >> 6, d0 = cc0 & 63;
    const int kk = d0 >> 5, lg = (d0 & 31) >> 3;   // j = d&7 == jj
#pragma unroll
    for (int ii = 0; ii < 8; ++ii) {
      const int r = m0 + ti * 8 + ii;
      const int bb = r >> 11, tt = r & 2047;
      const size_t base = (size_t)(bb * 8 + h) * 393216 +
                          (size_t)(tt >> 4) * 3072 + kk * 512 +
                          ((tt & 15) + 16 * lg) * 8;
      bf8 v1, v2, v3;
#pragma unroll
      for (int jj = 0; jj < 8; ++jj) {
        const float f = acc[ii][jj];
        const short s1 = f2bf(f);  const float r1 = f - bf2f(s1);
        const short s2 = f2bf(r1);
        const short s3 = f2bf(r1 - bf2f(s2));
        v1[jj] = s1; v2[jj] = s2; v3[jj] = s3;
      }
      *reinterpret_cast<bf8*>(KF + base)        = v1;
      *reinterpret_cast<bf8*>(KF + base + 1024) = v2;
      *reinterpret_cast<bf8*>(KF + base + 2048) = v3;
    }
  } else {
    const int t0r = m0 + ti * 8;                 // 8-aligned -> j = s&7 == ii
    const int bb = t0r >> 11, tt0 = t0r & 2047;
    const int cc = tt0 >> 5, lgs = (tt0 & 31) >> 3;
#pragma unroll
    for (int jj = 0; jj < 8; ++jj) {
      const int c = (n0 & 511) + tj * 8 + jj;
      const int h = c >> 6, dd = c & 63;
      bf8 pv;
#pragma unroll
      for (int ii = 0; ii < 8; ++ii) pv[ii] = f2bf(acc[ii][jj]);
      *reinterpret_cast<bf8*>(VF + (size_t)(bb * 8 + h) * 131072 +
                              cc * 2048 + (dd >> 4) * 512 +
                              ((dd & 15) + 16 * lgs) * 8) = pv;
    }
  }
}

// ---------------------------------------- K1': qkv GEMM via MFMA (main path)
// A = XS [3][8192][512], B = WqS [3][1536][512]; 6-term ladder, LV=3 STATIC
// for all parts (compile-time indexing only — no runtime-bound lev loops).
// Accs round-trip through LDS scratch so the proven (ti,tj) epilogue is reused.
__global__ __launch_bounds__(256) void qkv_mfma(
    const short* __restrict__ XS, const short* __restrict__ WqS,
    float* __restrict__ Qf32, short* __restrict__ KF, short* __restrict__ VF) {
  extern __shared__ char sm_[];
  short* As = (short*)sm_;                 // [3][128][40] bf16
  short* Bs = (short*)(sm_ + 30720);       // [3][128][40] bf16
  float* SC = (float*)sm_;                 // [128][132] f32 (after k-loop)
  const int t = threadIdx.x;
  const int w = t >> 6, lane = t & 63;
  const int lq = lane & 15, lg = lane >> 4;
  const int wr = w >> 1, wc = w & 1;
  const int n0 = blockIdx.x * 128, m0 = blockIdx.y * 128;
  const int part = n0 >> 9;                // 0=Q 1=K 2=V
  f32x4 acc[4][4];
#pragma unroll
  for (int i = 0; i < 4; ++i)
#pragma unroll
    for (int j2 = 0; j2 < 4; ++j2) acc[i][j2] = (f32x4){0.f, 0.f, 0.f, 0.f};
  const int sr = t >> 1, sh = (t & 1) * 16;
  for (int k0 = 0; k0 < 512; k0 += 32) {
#pragma unroll
    for (int lev = 0; lev < 3; ++lev) {
      const size_t xa = (size_t)lev * 4194304 + (size_t)(m0 + sr) * 512 + k0 + sh;
      *reinterpret_cast<bf8*>(&As[(lev * 128 + sr) * 40 + sh])     =
          *reinterpret_cast<const bf8*>(XS + xa);
      *reinterpret_cast<bf8*>(&As[(lev * 128 + sr) * 40 + sh + 8]) =
          *reinterpret_cast<const bf8*>(XS + xa + 8);
      const size_t wa = (size_t)lev * 786432 + (size_t)(n0 + sr) * 512 + k0 + sh;
      *reinterpret_cast<bf8*>(&Bs[(lev * 128 + sr) * 40 + sh])     =
          *reinterpret_cast<const bf8*>(WqS + wa);
      *reinterpret_cast<bf8*>(&Bs[(lev * 128 + sr) * 40 + sh + 8]) =
          *reinterpret_cast<const bf8*>(WqS + wa + 8);
    }
    __syncthreads();
    bf8 bfr[4][3];
#pragma unroll
    for (int i = 0; i < 4; ++i)
#pragma unroll
      for (int lev = 0; lev < 3; ++lev)
        bfr[i][lev] = *reinterpret_cast<const bf8*>(
            &Bs[(lev * 128 + wc * 64 + i * 16 + lq) * 40 + lg * 8]);
#pragma unroll
    for (int mi = 0; mi < 4; ++mi) {
      bf8 af0 = *reinterpret_cast<const bf8*>(
          &As[(0 * 128 + wr * 64 + mi * 16 + lq) * 40 + lg * 8]);
      bf8 af1 = *reinterpret_cast<const bf8*>(
          &As[(1 * 128 + wr * 64 + mi * 16 + lq) * 40 + lg * 8]);
      bf8 af2 = *reinterpret_cast<const bf8*>(
          &As[(2 * 128 + wr * 64 + mi * 16 + lq) * 40 + lg * 8]);
#pragma unroll
      for (int ni = 0; ni < 4; ++ni) {
        MFMA16(af0, bfr[ni][0], acc[mi][ni]);       // 1
        MFMA16(af0, bfr[ni][1], acc[mi][ni]);       // 2^-8
        MFMA16(af1, bfr[ni][0], acc[mi][ni]);       // 2^-8
        MFMA16(af1, bfr[ni][1], acc[mi][ni]);       // 2^-16
        MFMA16(af0, bfr[ni][2], acc[mi][ni]);       // 2^-16
        MFMA16(af2, bfr[ni][0], acc[mi][ni]);       // 2^-16
      }
    }
    __syncthreads();
  }
  // dump accs to scratch in (m,n) order
#pragma unroll
  for (int mi = 0; mi < 4; ++mi)
#pragma unroll
    for (int ni = 0; ni < 4; ++ni)
#pragma unroll
      for (int r = 0; r < 4; ++r)
        SC[(wr * 64 + mi * 16 + lg * 4 + r) * 132 + wc * 64 + ni * 16 + lq] =
            acc[mi][ni][r];
  __syncthreads();
  // epilogue: verbatim qkv_gemm scatter, accL re-read in (ti,tj) 8x8 order
  const int ti = t >> 4, tj = t & 15;
  float accL[8][8];
#pragma unroll
  for (int ii = 0; ii < 8; ++ii) {
    const float4 c0 = *reinterpret_cast<const float4*>(&SC[(ti * 8 + ii) * 132 + tj * 8]);
    const float4 c1 = *reinterpret_cast<const float4*>(&SC[(ti * 8 + ii) * 132 + tj * 8 + 4]);
    accL[ii][0] = c0.x; accL[ii][1] = c0.y; accL[ii][2] = c0.z; accL[ii][3] = c0.w;
    accL[ii][4] = c1.x; accL[ii][5] = c1.y; accL[ii][6] = c1.z; accL[ii][7] = c1.w;
  }
  if (part == 0) {
#pragma unroll
    for (int ii = 0; ii < 8; ++ii) {
      const int r = m0 + ti * 8 + ii;
      const int bb = r >> 11, tt = r & 2047;
#pragma unroll
      for (int jj = 0; jj < 8; ++jj) {
        const int c = (n0 & 511) + tj * 8 + jj;
        const int h = c >> 6, d = c & 63;
        Qf32[(size_t)(bb * 8 + h) * 131072 + (size_t)tt * 64 + d] =
            accL[ii][jj] * 0.125f;
      }
    }
  } else if (part == 1) {
    const int cc0 = (n0 & 511) + tj * 8;
    const int h = cc0 >> 6, d0 = cc0 & 63;
    const int kk = d0 >> 5, lg2 = (d0 & 31) >> 3;   // j = d&7 == jj
#pragma unroll
    for (int ii = 0; ii < 8; ++ii) {
      const int r = m0 + ti * 8 + ii;
      const int bb = r >> 11, tt = r & 2047;
      const size_t base = (size_t)(bb * 8 + h) * 393216 +
                          (size_t)(tt >> 4) * 3072 + kk * 512 +
                          ((tt & 15) + 16 * lg2) * 8;
      bf8 v1, v2, v3;
#pragma unroll
      for (int jj = 0; jj < 8; ++jj) {
        const float f = accL[ii][jj];
        const short s1 = f2bf(f);  const float r1 = f - bf2f(s1);
        const short s2 = f2bf(r1);
        const short s3 = f2bf(r1 - bf2f(s2));
        v1[jj] = s1; v2[jj] = s2; v3[jj] = s3;
      }
      *reinterpret_cast<bf8*>(KF + base)        = v1;
      *reinterpret_cast<bf8*>(KF + base + 1024) = v2;
      *reinterpret_cast<bf8*>(KF + base + 2048) = v3;
    }
  } else {
    const int t0r = m0 + ti * 8;                 // 8-aligned -> j = s&7 == ii
    const int bb = t0r >> 11, tt0 = t0r & 2047;
    const int cc = tt0 >> 5, lgs = (tt0 & 31) >> 3;
#pragma unroll
    for (int jj = 0; jj < 8; ++jj) {
      const int c = (n0 & 511) + tj * 8 + jj;
      const int h = c >> 6, dd = c & 63;
      bf8 pv;
#pragma unroll
      for (int ii = 0; ii < 8; ++ii) pv[ii] = f2bf(accL[ii][jj]);
      *reinterpret_cast<bf8*>(VF + (size_t)(bb * 8 + h) * 131072 +
                              cc * 2048 + (dd >> 4) * 512 +
                              ((dd & 15) + 16 * lgs) * 8) = pv;
    }
  }
}

// ------------------------------------------------------------- K3: out proj GEMM
__global__ __launch_bounds__(256) void out_mfma(
    const short* __restrict__ HOS, const short* __restrict__ WoS,
    float* __restrict__ OUT) {
  __shared__ short As[2][128][40];
  __shared__ short Bs[2][128][40];
  const int t = threadIdx.x;
  const int w = t >> 6, lane = t & 63;
  const int lq = lane & 15, lg = lane >> 4;
  const int wr = w >> 1, wc = w & 1;
  const int n0 = blockIdx.x * 128, m0 = blockIdx.y * 128;
  f32x4 acc[4][4];
#pragma unroll
  for (int i = 0; i < 4; ++i)
#pragma unroll
    for (int j2 = 0; j2 < 4; ++j2) acc[i][j2] = (f32x4){0.f, 0.f, 0.f, 0.f};
  const int sm = t >> 1, sh = (t & 1) * 16;
  for (int k0 = 0; k0 < 512; k0 += 32) {
#pragma unroll
    for (int lev = 0; lev < 2; ++lev) {
      const size_t xa = (size_t)lev * 4194304 + (size_t)(m0 + sm) * 512 + k0 + sh;
      *reinterpret_cast<bf8*>(&As[lev][sm][sh])     = *reinterpret_cast<const bf8*>(HOS + xa);
      *reinterpret_cast<bf8*>(&As[lev][sm][sh + 8]) = *reinterpret_cast<const bf8*>(HOS + xa + 8);
      const size_t wa = (size_t)lev * 262144 + (size_t)(n0 + sm) * 512 + k0 + sh;
      *reinterpret_cast<bf8*>(&Bs[lev][sm][sh])     = *reinterpret_cast<const bf8*>(WoS + wa);
      *reinterpret_cast<bf8*>(&Bs[lev][sm][sh + 8]) = *reinterpret_cast<const bf8*>(WoS + wa + 8);
    }
    __syncthreads();
    bf8 af[4][2], bfr[4][2];
#pragma unroll
    for (int i = 0; i < 4; ++i)
#pragma unroll
      for (int lev = 0; lev < 2; ++lev) {
        af[i][lev]  = *reinterpret_cast<const bf8*>(&As[lev][wr * 64 + i * 16 + lq][lg * 8]);
        bfr[i][lev] = *reinterpret_cast<const bf8*>(&Bs[lev][wc * 64 + i * 16 + lq][lg * 8]);
      }
#pragma unroll
    for (int mi = 0; mi < 4; ++mi)
#pragma unroll
      for (int ni = 0; ni < 4; ++ni) {
        MFMA16(af[mi][0], bfr[ni][0], acc[mi][ni]);
        MFMA16(af[mi][0], bfr[ni][1], acc[mi][ni]);
        MFMA16(af[mi][1], bfr[ni][0], acc[mi][ni]);
      }
    __syncthreads();
  }
#pragma unroll
  for (int mi = 0; mi < 4; ++mi)
#pragma unroll
    for (int r = 0; r < 4; ++r) {
      const int m = m0 + wr * 64 + mi * 16 + lg * 4 + r;
#pragma unroll
      for (int ni = 0; ni < 4; ++ni)
        OUT[(size_t)m * 512 + n0 + wc * 64 + ni * 16 + lq] = acc[mi][ni][r];
    }
}

// ---------------------------------------------------------------- K2: attention
// 512 threads = 8 waves; 8 q-rows/block; 64 KB LDS -> 2 blocks/CU.
// Lanes lq>=8 duplicate rows 0-7 (row = lq&7): same-address/same-value LDS
// writes in P1, duplicate (discarded) MFMA rows in P3.
__global__ __launch_bounds__(512, 4) void attn_mfma(
    const float* __restrict__ Qf32, const short* __restrict__ KF,
    const short* __restrict__ VF, const float* __restrict__ alpha,
    short* __restrict__ HOS) {
  extern __shared__ char lds[];
  const int tid = threadIdx.x;
  const int w = tid >> 6, lane = tid & 63;      // w in [0,8)
  const int lq = lane & 15, lg = lane >> 4;
  const int row = lq & 7;

  // XCD swizzle: 8192 blocks, 1024/XCD = 4 bh x 256 qb
  const int flat = blockIdx.x + (int)gridDim.x * blockIdx.y;
  const int xcd = flat & 7, idx = flat >> 3;
  const int bh = xcd * 4 + (idx >> 8);
  const int qb = idx & 255;
  const int b = bh >> 3, h = bh & 7;
  const int q0 = qb * 8;

  const float gate = 1.0f / (1.0f + __expf(-alpha[h]));
  const int key = row;                           // row's swizzle key (row < 8)

  // Q fragments: load f32 row q0+row, split 3-level in-register
  bf8 qf[3][2];
  {
    const float* qp = Qf32 + (size_t)bh * 131072 + (size_t)(q0 + row) * 64 + lg * 8;
#pragma unroll
    for (int kk = 0; kk < 2; ++kk) {
      const float4 g0 = *reinterpret_cast<const float4*>(qp + kk * 32);
      const float4 g1 = *reinterpret_cast<const float4*>(qp + kk * 32 + 4);
      const float v[8] = {g0.x, g0.y, g0.z, g0.w, g1.x, g1.y, g1.z, g1.w};
#pragma unroll
      for (int e = 0; e < 8; ++e) {
        const short s1 = f2bf(v[e]);  const float r1 = v[e] - bf2f(s1);
        const short s2 = f2bf(r1);
        const short s3 = f2bf(r1 - bf2f(s2));
        qf[0][kk][e] = s1; qf[1][kk][e] = s2; qf[2][kk][e] = s3;
      }
    }
  }

  auto ldk = [&](int t, bf8 (&dst)[3][2]) {
    const short* p = KF + (size_t)(bh * 128 + t) * 3072 + lane * 8;
    dst[0][0] = *reinterpret_cast<const bf8*>(p);
    dst[0][1] = *reinterpret_cast<const bf8*>(p + 512);
    dst[1][0] = *reinterpret_cast<const bf8*>(p + 1024);
    dst[1][1] = *reinterpret_cast<const bf8*>(p + 1536);
    dst[2][0] = *reinterpret_cast<const bf8*>(p + 2048);
    dst[2][1] = *reinterpret_cast<const bf8*>(p + 2560);
  };
  auto qk = [&](bf8 (&kf)[3][2], int t) {
    f32x4 c0 = {0.f,0.f,0.f,0.f}, c1 = {0.f,0.f,0.f,0.f}, c2 = {0.f,0.f,0.f,0.f};
#pragma unroll
    for (int kk = 0; kk < 2; ++kk) {
      MFMA16(kf[0][kk], qf[0][kk], c0);   // 1
      MFMA16(kf[0][kk], qf[1][kk], c1);   // 2^-8
      MFMA16(kf[1][kk], qf[0][kk], c1);   // 2^-8
      MFMA16(kf[1][kk], qf[1][kk], c2);   // 2^-16
      MFMA16(kf[0][kk], qf[2][kk], c2);   // 2^-16
      MFMA16(kf[2][kk], qf[0][kk], c2);   // 2^-16
    }
    const f32x4 c = (c0 + c1) + c2;
    // lanes lq>=8 write the same address+value as their lq-8 twin (benign)
    *reinterpret_cast<f32x4*>(
        lds + row * 8192 + ((((t << 2) + lg) ^ key) << 4)) = c;
  };

  // ---- P1: logits (double-buffered, 16 tiles/wave)
  {
    bf8 ka[3][2], kb[3][2];
    ldk(w, ka);
#pragma unroll
    for (int j = 0; j < 16; j += 2) {
      const int t0 = w + 8 * j;
      ldk(t0 + 8, kb);
      qk(ka, t0);
      if (j + 2 < 16) ldk(t0 + 16, ka);
      qk(kb, t0 + 8);
    }
  }
  __syncthreads();

  // V prefetch for P3 chunk w (latency hidden under P2)
  bf8 va[4], vb[4];
  auto ldv = [&](int cc, bf8 (&dst)[4]) {
    const short* p = VF + (size_t)(bh * 64 + cc) * 2048 + lane * 8;
    dst[0] = *reinterpret_cast<const bf8*>(p);
    dst[1] = *reinterpret_cast<const bf8*>(p + 512);
    dst[2] = *reinterpret_cast<const bf8*>(p + 1024);
    dst[3] = *reinterpret_cast<const bf8*>(p + 1536);
  };
  ldv(w, va);

  // ---- P2: wave w owns row q=w. Exact top-64 threshold; counts via
  // ballot+popcount (SALU) instead of per-lane add + shfl reduce chains.
  {
    const int q = w;
    const int rkey = q & 7;
    const char* rowb = lds + q * 8192;
    unsigned uv[32];
    float lm = -3.402823466e+38f;
#pragma unroll
    for (int jj = 0; jj < 8; ++jj) {
      const f32x4 v = *reinterpret_cast<const f32x4*>(rowb + ((lane + 64 * jj) << 4));
#pragma unroll
      for (int e = 0; e < 4; ++e) {
        const float a = v[e];
        lm = fmaxf(lm, a);
        const unsigned fb = __float_as_uint(a);
        uv[jj * 4 + e] = (fb & 0x80000000u) ? ~fb : (fb | 0x80000000u);
      }
    }
    // m = global max; g0 = min of per-lane maxima -> cnt(>=g0) >= 64,
    // so the 64th-largest lies in [g0, m].
    float m = lm, g0 = lm;
#pragma unroll
    for (int off = 32; off; off >>= 1) m = fmaxf(m, __shfl_xor(m, off));
#pragma unroll
    for (int off = 32; off; off >>= 1) g0 = fminf(g0, __shfl_xor(g0, off));
    float ev[32]; float dsum = 0.f;
#pragma unroll
    for (int j = 0; j < 32; ++j) {
      const unsigned u = uv[j];
      const float a = __uint_as_float((u & 0x80000000u) ? (u & 0x7fffffffu) : ~u);
      ev[j] = __expf(a - m);
      dsum += ev[j];
    }
#pragma unroll
    for (int off = 32; off; off >>= 1) dsum += __shfl_xor(dsum, off);
    const unsigned um_ = __float_as_uint(m);
    const unsigned ug_ = __float_as_uint(g0);
    // scalarize bounds: loop control + candidates live entirely in SGPRs
    unsigned lo = __builtin_amdgcn_readfirstlane(
        (ug_ & 0x80000000u) ? ~ug_ : (ug_ | 0x80000000u));
    unsigned hi = __builtin_amdgcn_readfirstlane(
        (um_ & 0x80000000u) ? ~um_ : (um_ | 0x80000000u));
    // invariant: cnt(>= lo) >= 64. Find max T with cnt(>= T) >= 64.
    while (lo < hi) {
      const unsigned mid = lo + ((hi - lo + 1) >> 1);   // mid in (lo, hi]
      int cnt = 0;
#pragma unroll
      for (int j = 0; j < 32; ++j)
        cnt += (int)__popcll(__ballot(uv[j] >= mid));
      if (cnt >= 64) {
        lo = mid;
        if (cnt == 64) break;
      } else {
        hi = mid - 1;
      }
    }
    const unsigned thr = lo;
    float ssum = 0.f;
#pragma unroll
    for (int j = 0; j < 32; ++j) ssum += (uv[j] >= thr) ? ev[j] : 0.f;
#pragma unroll
    for (int off = 32; off; off >>= 1) ssum += __shfl_xor(ssum, off);
    const float dinv = gate / dsum;
    const float sinv = (1.0f - gate) / ssum;
#pragma unroll
    for (int jj = 0; jj < 8; ++jj) {
      const int p = lane + 64 * jj;
      const int f = p ^ rkey;
      const float w0 = ev[jj*4+0] * (dinv + ((uv[jj*4+0] >= thr) ? sinv : 0.f));
      const float w1 = ev[jj*4+1] * (dinv + ((uv[jj*4+1] >= thr) ? sinv : 0.f));
      const float w2 = ev[jj*4+2] * (dinv + ((uv[jj*4+2] >= thr) ? sinv : 0.f));
      const float w3 = ev[jj*4+3] * (dinv + ((uv[jj*4+3] >= thr) ? sinv : 0.f));
      uint2 pk;
      pk.x = (unsigned)(unsigned short)f2bf(w0) |
             ((unsigned)(unsigned short)f2bf(w1) << 16);
      pk.y = (unsigned)(unsigned short)f2bf(w2) |
             ((unsigned)(unsigned short)f2bf(w3) << 16);
      *reinterpret_cast<uint2*>(
          lds + q * 8192 + ((((f >> 1) ^ rkey) << 4) + ((f & 1) << 3))) = pk;
    }
  }
  __syncthreads();

  // ---- P3: PV. wave w does s-chunks cc = w + 8j (8 chunks of 32 s), 4 d-tiles.
  f32x4 o0 = {0.f,0.f,0.f,0.f}, o1 = {0.f,0.f,0.f,0.f};
  f32x4 o2 = {0.f,0.f,0.f,0.f}, o3 = {0.f,0.f,0.f,0.f};
  {
    auto pv = [&](bf8 (&vv)[4], int cc) {
      const bf8 pa = *reinterpret_cast<const bf8*>(
          lds + row * 8192 + ((((cc << 2) + lg) ^ key) << 4));
      MFMA16(pa, vv[0], o0);
      MFMA16(pa, vv[1], o1);
      MFMA16(pa, vv[2], o2);
      MFMA16(pa, vv[3], o3);
    };
#pragma unroll
    for (int j = 0; j < 8; j += 2) {
      const int cc = w + 8 * j;
      ldv(cc + 8, vb);
      pv(va, cc);
      if (j + 2 < 8) ldv(cc + 16, va);
      pv(vb, cc + 8);
    }
  }
  // park partials: tile = w*4+dt in [0,32): row tile&7, slot tile>>3
  {
    const f32x4 oo[4] = {o0, o1, o2, o3};
#pragma unroll
    for (int dt = 0; dt < 4; ++dt) {
      const int tile = w * 4 + dt;
      char* pb = lds + (tile & 7) * 8192 + 4096 + ((tile >> 3) << 10);
#pragma unroll
      for (int r = 0; r < 4; ++r)
        *reinterpret_cast<float*>(pb + (((lg * 4 + r) * 16 + lq) << 2)) = oo[dt][r];
    }
  }
  __syncthreads();
  // reduce 8 wave-partials, write HOS (2-level bf16). 512 thr = 8 q x 64 d.
  {
    const int q = tid >> 6, d = tid & 63;
    const int dt = d >> 4;
    float s = 0.f;
#pragma unroll
    for (int ww = 0; ww < 8; ++ww) {
      const int tile = ww * 4 + dt;
      s += *reinterpret_cast<const float*>(
          lds + (tile & 7) * 8192 + 4096 + ((tile >> 3) << 10) +
          ((q * 16 + (d & 15)) << 2));
    }
    const size_t o = (size_t)(b * TSEQ + q0 + q) * 512 + h * 64 + d;
    const short s1 = f2bf(s);
    HOS[o] = s1;
    HOS[o + 4194304] = f2bf(s - bf2f(s1));
  }
}

// ------------------------------------------------------------------- launcher
extern "C" void kernel_launch(void* const* d_in, const int* in_sizes, int n_in,
                              void* d_out, int out_size, void* d_ws, size_t ws_size,
                              hipStream_t stream) {
  const float* x     = (const float*)d_in[0];
  const float* Wqkv  = (const float*)d_in[1];
  const float* Wout  = (const float*)d_in[2];
  const float* alpha = (const float*)d_in[3];
  float* out = (float*)d_out;

  float* Qf32 = (float*)d_ws;
  short* S16  = (short*)d_ws;
  short* KF   = S16 + 8388608;
  short* VF   = S16 + 20971520;
  short* HOS  = S16 + 25165824;
  short* WoS  = S16 + 33554432;
  short* WqS  = S16 + 34078720;   // 3 x 1536 x 512
  short* XSp  = S16 + 36438016;   // 3 x 8192 x 512

  const int attn_lds = 65536;
  (void)hipFuncSetAttribute((const void*)attn_mfma,
                            hipFuncAttributeMaxDynamicSharedMemorySize, attn_lds);

  transpose_split<<<dim3(4, 16), 256, 0, stream>>>(Wout, WoS, 512, 512);

  const bool big = ws_size >= (size_t)98041856;
  if (big) {
    transpose_split3<<<dim3(12, 16), 256, 0, stream>>>(Wqkv, WqS, 512, 1536);
    xsplit3<<<2048, 256, 0, stream>>>(x, XSp);
    const int qkv_lds = 67584;
    (void)hipFuncSetAttribute((const void*)qkv_mfma,
                              hipFuncAttributeMaxDynamicSharedMemorySize, qkv_lds);
    qkv_mfma<<<dim3(12, 64), 256, qkv_lds, stream>>>(XSp, WqS, Qf32, KF, VF);
  } else {
    qkv_gemm<<<dim3(12, 64), 256, 0, stream>>>(x, Wqkv, Qf32, KF, VF);
  }
  attn_mfma<<<dim3(256, 32), 512, attn_lds, stream>>>(Qf32, KF, VF, alpha, HOS);
  out_mfma<<<dim3(4, 64), 256, 0, stream>>>(HOS, WoS, out);
}

// Round 4
// 493.344 us; speedup vs baseline: 3.0988x; 1.0143x over previous
//
#include <hip/hip_runtime.h>
#include <hip/hip_bf16.h>
#include <cstdint>
#include <cstddef>

// AdaptiveSparseSelfAttention — round 12: attn P2 selection in float space.
// The R9 integer-ULP bisection needed a monotone uint mapping pass (~96 ops),
// a float re-decode in the exp pass (~96 ops), and ~14 ULP-space probes.
// Value-space float bisection reaches the (v65,v64] gap in ~7 probes (the
// cnt==64 early-exit is the common exit), compares floats directly, and the
// mapping/decode passes die. Selected set is provably identical (adjacent-
// float brackets converge to v64 exactly; bit-duplicate ties behave as in
// R9). Weight pack now uses __float22bfloat162_rn (packed RNE = f2bf bitwise).
// All other kernels byte-identical to R11.
//
// ws layout (98,041,856 B total when big path active):
//   Qf32 f32  [32][2048][64]                4,194,304 f  @ short 0
//   KF   bf16 [32][128 kt][3][2][64][8]    12,582,912 s  @ short 8,388,608
//   VF   bf16 [32][64 cc][4 dt][64][8]      4,194,304 s  @ short 20,971,520
//   HOS  bf16 [2 lev][8192][512]            8,388,608 s  @ short 25,165,824
//   WoS  bf16 [2 lev][512][512]               524,288 s  @ short 33,554,432
//   WqS  bf16 [3 lev][1536][512]            2,359,296 s  @ short 34,078,720
//   XS   bf16 [3 lev][8192][512]           12,582,912 s  @ short 36,438,016

#define TSEQ 2048

typedef __attribute__((ext_vector_type(8))) short bf8;
typedef __attribute__((ext_vector_type(4))) float f32x4;

#define MFMA16(A, B, C) \
  C = __builtin_amdgcn_mfma_f32_16x16x32_bf16(A, B, C, 0, 0, 0)

static __device__ __forceinline__ short f2bf(float f) {
  unsigned u = __float_as_uint(f);
  u += 0x7FFFu + ((u >> 16) & 1u);
  return (short)(u >> 16);
}
static __device__ __forceinline__ float bf2f(short s) {
  return __uint_as_float(((unsigned)(unsigned short)s) << 16);
}
static __device__ __forceinline__ unsigned pack_bf16x2(float a, float b) {
  float2 f2; f2.x = a; f2.y = b;
  __hip_bfloat162 h = __float22bfloat162_rn(f2);   // RNE, same bits as f2bf
  unsigned r;
  __builtin_memcpy(&r, &h, 4);
  return r;
}

// ---------------------------------------- prep: transpose + split weight matrix
// W[K][N] -> out[lev][N][K], lev stride N*K (2 levels, for Wout)
__global__ __launch_bounds__(256) void transpose_split(
    const float* __restrict__ W, short* __restrict__ out, int K, int N) {
  __shared__ float tile[32][129];
  const int t = threadIdx.x;
  const int nb = blockIdx.x * 128, kb = blockIdx.y * 32;
#pragma unroll
  for (int c = 0; c < 4; ++c) {
    const int flat = c * 256 + t;
    const int r = flat >> 5, nq = (flat & 31) * 4;
    const float4 g = *reinterpret_cast<const float4*>(&W[(size_t)(kb + r) * N + nb + nq]);
    tile[r][nq] = g.x; tile[r][nq + 1] = g.y;
    tile[r][nq + 2] = g.z; tile[r][nq + 3] = g.w;
  }
  __syncthreads();
  const int n = t >> 1, kh = (t & 1) * 16;
  bf8 a0, a1, b0, b1;
#pragma unroll
  for (int e = 0; e < 16; ++e) {
    const float f = tile[kh + e][n];
    const short s1 = f2bf(f);
    const short s2 = f2bf(f - bf2f(s1));
    if (e < 8) { a0[e] = s1; b0[e] = s2; }
    else       { a1[e - 8] = s1; b1[e - 8] = s2; }
  }
  const size_t o = (size_t)(nb + n) * K + kb + kh;
  const size_t ls = (size_t)N * K;
  *reinterpret_cast<bf8*>(out + o) = a0;
  *reinterpret_cast<bf8*>(out + o + 8) = a1;
  *reinterpret_cast<bf8*>(out + o + ls) = b0;
  *reinterpret_cast<bf8*>(out + o + ls + 8) = b1;
}

// 3-level variant (for Wqkv): W[K][N] -> out[lev][N][K], lev stride N*K
__global__ __launch_bounds__(256) void transpose_split3(
    const float* __restrict__ W, short* __restrict__ out, int K, int N) {
  __shared__ float tile[32][129];
  const int t = threadIdx.x;
  const int nb = blockIdx.x * 128, kb = blockIdx.y * 32;
#pragma unroll
  for (int c = 0; c < 4; ++c) {
    const int flat = c * 256 + t;
    const int r = flat >> 5, nq = (flat & 31) * 4;
    const float4 g = *reinterpret_cast<const float4*>(&W[(size_t)(kb + r) * N + nb + nq]);
    tile[r][nq] = g.x; tile[r][nq + 1] = g.y;
    tile[r][nq + 2] = g.z; tile[r][nq + 3] = g.w;
  }
  __syncthreads();
  const int n = t >> 1, kh = (t & 1) * 16;
  bf8 a0, a1, b0, b1, c0, c1;
#pragma unroll
  for (int e = 0; e < 16; ++e) {
    const float f = tile[kh + e][n];
    const short s1 = f2bf(f);  const float r1 = f - bf2f(s1);
    const short s2 = f2bf(r1);
    const short s3 = f2bf(r1 - bf2f(s2));
    if (e < 8) { a0[e] = s1; b0[e] = s2; c0[e] = s3; }
    else       { a1[e - 8] = s1; b1[e - 8] = s2; c1[e - 8] = s3; }
  }
  const size_t o = (size_t)(nb + n) * K + kb + kh;
  const size_t ls = (size_t)N * K;
  *reinterpret_cast<bf8*>(out + o) = a0;
  *reinterpret_cast<bf8*>(out + o + 8) = a1;
  *reinterpret_cast<bf8*>(out + o + ls) = b0;
  *reinterpret_cast<bf8*>(out + o + ls + 8) = b1;
  *reinterpret_cast<bf8*>(out + o + 2 * ls) = c0;
  *reinterpret_cast<bf8*>(out + o + 2 * ls + 8) = c1;
}

// prep: X[8192][512] f32 -> XS[3][8192][512] bf16 (3-level split, row-major)
__global__ __launch_bounds__(256) void xsplit3(
    const float* __restrict__ X, short* __restrict__ XS) {
  const int i = (blockIdx.x * 256 + threadIdx.x) * 8;
  const float4 g0 = *reinterpret_cast<const float4*>(X + i);
  const float4 g1 = *reinterpret_cast<const float4*>(X + i + 4);
  const float v[8] = {g0.x, g0.y, g0.z, g0.w, g1.x, g1.y, g1.z, g1.w};
  bf8 s1v, s2v, s3v;
#pragma unroll
  for (int e = 0; e < 8; ++e) {
    const short s1 = f2bf(v[e]);  const float r1 = v[e] - bf2f(s1);
    const short s2 = f2bf(r1);
    const short s3 = f2bf(r1 - bf2f(s2));
    s1v[e] = s1; s2v[e] = s2; s3v[e] = s3;
  }
  *reinterpret_cast<bf8*>(XS + i)           = s1v;
  *reinterpret_cast<bf8*>(XS + i + 4194304) = s2v;
  *reinterpret_cast<bf8*>(XS + i + 8388608) = s3v;
}

// ---------------------------------------------------------------- K1: qkv GEMM
// Fallback path: f32 VALU (R4-proven numerics).
__global__ __launch_bounds__(256) void qkv_gemm(
    const float* __restrict__ X, const float* __restrict__ W,
    float* __restrict__ Qf32, short* __restrict__ KF, short* __restrict__ VF) {
  __shared__ float As[16][132];
  __shared__ float Bs[16][132];
  const int t = threadIdx.x;
  const int n0 = blockIdx.x * 128;
  const int m0 = blockIdx.y * 128;
  const int ti = t >> 4, tj = t & 15;
  float acc[8][8] = {};
  for (int kt = 0; kt < 512; kt += 16) {
#pragma unroll
    for (int e = 0; e < 2; ++e) {
      int idx = e * 256 + t;
      int m = idx >> 2, kq = (idx & 3) << 2;
      const float4 g = *reinterpret_cast<const float4*>(
          &X[(size_t)(m0 + m) * 512 + kt + kq]);
      As[kq + 0][m] = g.x; As[kq + 1][m] = g.y;
      As[kq + 2][m] = g.z; As[kq + 3][m] = g.w;
    }
#pragma unroll
    for (int e = 0; e < 2; ++e) {
      int idx = e * 256 + t;
      int kk = idx >> 5, n4 = (idx & 31) << 2;
      *reinterpret_cast<float4*>(&Bs[kk][n4]) =
          *reinterpret_cast<const float4*>(&W[(size_t)(kt + kk) * 1536 + n0 + n4]);
    }
    __syncthreads();
#pragma unroll
    for (int kk = 0; kk < 16; ++kk) {
      const float4 A0 = *reinterpret_cast<const float4*>(&As[kk][ti * 8]);
      const float4 A1 = *reinterpret_cast<const float4*>(&As[kk][ti * 8 + 4]);
      const float4 B0 = *reinterpret_cast<const float4*>(&Bs[kk][tj * 8]);
      const float4 B1 = *reinterpret_cast<const float4*>(&Bs[kk][tj * 8 + 4]);
      const float a[8] = {A0.x, A0.y, A0.z, A0.w, A1.x, A1.y, A1.z, A1.w};
      const float b[8] = {B0.x, B0.y, B0.z, B0.w, B1.x, B1.y, B1.z, B1.w};
#pragma unroll
      for (int ii = 0; ii < 8; ++ii)
#pragma unroll
        for (int jj = 0; jj < 8; ++jj)
          acc[ii][jj] = fmaf(a[ii], b[jj], acc[ii][jj]);
    }
    __syncthreads();
  }
  const int part = n0 >> 9;     // 0=Q 1=K 2=V
  if (part == 0) {
#pragma unroll
    for (int ii = 0; ii < 8; ++ii) {
      const int r = m0 + ti * 8 + ii;
      const int bb = r >> 11, tt = r & 2047;
#pragma unroll
      for (int jj = 0; jj < 8; ++jj) {
        const int c = (n0 & 511) + tj * 8 + jj;
        const int h = c >> 6, d = c & 63;
        Qf32[(size_t)(bb * 8 + h) * 131072 + (size_t)tt * 64 + d] =
            acc[ii][jj] * 0.125f;
      }
    }
  } else if (part == 1) {
    const int cc0 = (n0 & 511) + tj * 8;
    const int h = cc0 >> 6, d0 = cc0 & 63;
    const int kk = d0 >> 5, lg = (d0 & 31) >> 3;   // j = d&7 == jj
#pragma unroll
    for (int ii = 0; ii < 8; ++ii) {
      const int r = m0 + ti * 8 + ii;
      const int bb = r >> 11, tt = r & 2047;
      const size_t base = (size_t)(bb * 8 + h) * 393216 +
                          (size_t)(tt >> 4) * 3072 + kk * 512 +
                          ((tt & 15) + 16 * lg) * 8;
      bf8 v1, v2, v3;
#pragma unroll
      for (int jj = 0; jj < 8; ++jj) {
        const float f = acc[ii][jj];
        const short s1 = f2bf(f);  const float r1 = f - bf2f(s1);
        const short s2 = f2bf(r1);
        const short s3 = f2bf(r1 - bf2f(s2));
        v1[jj] = s1; v2[jj] = s2; v3[jj] = s3;
      }
      *reinterpret_cast<bf8*>(KF + base)        = v1;
      *reinterpret_cast<bf8*>(KF + base + 1024) = v2;
      *reinterpret_cast<bf8*>(KF + base + 2048) = v3;
    }
  } else {
    const int t0r = m0 + ti * 8;                 // 8-aligned -> j = s&7 == ii
    const int bb = t0r >> 11, tt0 = t0r & 2047;
    const int cc = tt0 >> 5, lgs = (tt0 & 31) >> 3;
#pragma unroll
    for (int jj = 0; jj < 8; ++jj) {
      const int c = (n0 & 511) + tj * 8 + jj;
      const int h = c >> 6, dd = c & 63;
      bf8 pv;
#pragma unroll
      for (int ii = 0; ii < 8; ++ii) pv[ii] = f2bf(acc[ii][jj]);
      *reinterpret_cast<bf8*>(VF + (size_t)(bb * 8 + h) * 131072 +
                              cc * 2048 + (dd >> 4) * 512 +
                              ((dd & 15) + 16 * lgs) * 8) = pv;
    }
  }
}

// ---------------------------------------- K1': qkv GEMM via MFMA (main path)
// A = XS [3][8192][512], B = WqS [3][1536][512]; 6-term ladder, LV=3 STATIC
// for all parts (compile-time indexing only — no runtime-bound lev loops).
// Accs round-trip through LDS scratch so the proven (ti,tj) epilogue is reused.
__global__ __launch_bounds__(256) void qkv_mfma(
    const short* __restrict__ XS, const short* __restrict__ WqS,
    float* __restrict__ Qf32, short* __restrict__ KF, short* __restrict__ VF) {
  extern __shared__ char sm_[];
  short* As = (short*)sm_;                 // [3][128][40] bf16
  short* Bs = (short*)(sm_ + 30720);       // [3][128][40] bf16
  float* SC = (float*)sm_;                 // [128][132] f32 (after k-loop)
  const int t = threadIdx.x;
  const int w = t >> 6, lane = t & 63;
  const int lq = lane & 15, lg = lane >> 4;
  const int wr = w >> 1, wc = w & 1;
  const int n0 = blockIdx.x * 128, m0 = blockIdx.y * 128;
  const int part = n0 >> 9;                // 0=Q 1=K 2=V
  f32x4 acc[4][4];
#pragma unroll
  for (int i = 0; i < 4; ++i)
#pragma unroll
    for (int j2 = 0; j2 < 4; ++j2) acc[i][j2] = (f32x4){0.f, 0.f, 0.f, 0.f};
  const int sr = t >> 1, sh = (t & 1) * 16;
  for (int k0 = 0; k0 < 512; k0 += 32) {
#pragma unroll
    for (int lev = 0; lev < 3; ++lev) {
      const size_t xa = (size_t)lev * 4194304 + (size_t)(m0 + sr) * 512 + k0 + sh;
      *reinterpret_cast<bf8*>(&As[(lev * 128 + sr) * 40 + sh])     =
          *reinterpret_cast<const bf8*>(XS + xa);
      *reinterpret_cast<bf8*>(&As[(lev * 128 + sr) * 40 + sh + 8]) =
          *reinterpret_cast<const bf8*>(XS + xa + 8);
      const size_t wa = (size_t)lev * 786432 + (size_t)(n0 + sr) * 512 + k0 + sh;
      *reinterpret_cast<bf8*>(&Bs[(lev * 128 + sr) * 40 + sh])     =
          *reinterpret_cast<const bf8*>(WqS + wa);
      *reinterpret_cast<bf8*>(&Bs[(lev * 128 + sr) * 40 + sh + 8]) =
          *reinterpret_cast<const bf8*>(WqS + wa + 8);
    }
    __syncthreads();
    bf8 bfr[4][3];
#pragma unroll
    for (int i = 0; i < 4; ++i)
#pragma unroll
      for (int lev = 0; lev < 3; ++lev)
        bfr[i][lev] = *reinterpret_cast<const bf8*>(
            &Bs[(lev * 128 + wc * 64 + i * 16 + lq) * 40 + lg * 8]);
#pragma unroll
    for (int mi = 0; mi < 4; ++mi) {
      bf8 af0 = *reinterpret_cast<const bf8*>(
          &As[(0 * 128 + wr * 64 + mi * 16 + lq) * 40 + lg * 8]);
      bf8 af1 = *reinterpret_cast<const bf8*>(
          &As[(1 * 128 + wr * 64 + mi * 16 + lq) * 40 + lg * 8]);
      bf8 af2 = *reinterpret_cast<const bf8*>(
          &As[(2 * 128 + wr * 64 + mi * 16 + lq) * 40 + lg * 8]);
#pragma unroll
      for (int ni = 0; ni < 4; ++ni) {
        MFMA16(af0, bfr[ni][0], acc[mi][ni]);       // 1
        MFMA16(af0, bfr[ni][1], acc[mi][ni]);       // 2^-8
        MFMA16(af1, bfr[ni][0], acc[mi][ni]);       // 2^-8
        MFMA16(af1, bfr[ni][1], acc[mi][ni]);       // 2^-16
        MFMA16(af0, bfr[ni][2], acc[mi][ni]);       // 2^-16
        MFMA16(af2, bfr[ni][0], acc[mi][ni]);       // 2^-16
      }
    }
    __syncthreads();
  }
  // dump accs to scratch in (m,n) order
#pragma unroll
  for (int mi = 0; mi < 4; ++mi)
#pragma unroll
    for (int ni = 0; ni < 4; ++ni)
#pragma unroll
      for (int r = 0; r < 4; ++r)
        SC[(wr * 64 + mi * 16 + lg * 4 + r) * 132 + wc * 64 + ni * 16 + lq] =
            acc[mi][ni][r];
  __syncthreads();
  // epilogue: verbatim qkv_gemm scatter, accL re-read in (ti,tj) 8x8 order
  const int ti = t >> 4, tj = t & 15;
  float accL[8][8];
#pragma unroll
  for (int ii = 0; ii < 8; ++ii) {
    const float4 c0 = *reinterpret_cast<const float4*>(&SC[(ti * 8 + ii) * 132 + tj * 8]);
    const float4 c1 = *reinterpret_cast<const float4*>(&SC[(ti * 8 + ii) * 132 + tj * 8 + 4]);
    accL[ii][0] = c0.x; accL[ii][1] = c0.y; accL[ii][2] = c0.z; accL[ii][3] = c0.w;
    accL[ii][4] = c1.x; accL[ii][5] = c1.y; accL[ii][6] = c1.z; accL[ii][7] = c1.w;
  }
  if (part == 0) {
#pragma unroll
    for (int ii = 0; ii < 8; ++ii) {
      const int r = m0 + ti * 8 + ii;
      const int bb = r >> 11, tt = r & 2047;
#pragma unroll
      for (int jj = 0; jj < 8; ++jj) {
        const int c = (n0 & 511) + tj * 8 + jj;
        const int h = c >> 6, d = c & 63;
        Qf32[(size_t)(bb * 8 + h) * 131072 + (size_t)tt * 64 + d] =
            accL[ii][jj] * 0.125f;
      }
    }
  } else if (part == 1) {
    const int cc0 = (n0 & 511) + tj * 8;
    const int h = cc0 >> 6, d0 = cc0 & 63;
    const int kk = d0 >> 5, lg2 = (d0 & 31) >> 3;   // j = d&7 == jj
#pragma unroll
    for (int ii = 0; ii < 8; ++ii) {
      const int r = m0 + ti * 8 + ii;
      const int bb = r >> 11, tt = r & 2047;
      const size_t base = (size_t)(bb * 8 + h) * 393216 +
                          (size_t)(tt >> 4) * 3072 + kk * 512 +
                          ((tt & 15) + 16 * lg2) * 8;
      bf8 v1, v2, v3;
#pragma unroll
      for (int jj = 0; jj < 8; ++jj) {
        const float f = accL[ii][jj];
        const short s1 = f2bf(f);  const float r1 = f - bf2f(s1);
        const short s2 = f2bf(r1);
        const short s3 = f2bf(r1 - bf2f(s2));
        v1[jj] = s1; v2[jj] = s2; v3[jj] = s3;
      }
      *reinterpret_cast<bf8*>(KF + base)        = v1;
      *reinterpret_cast<bf8*>(KF + base + 1024) = v2;
      *reinterpret_cast<bf8*>(KF + base + 2048) = v3;
    }
  } else {
    const int t0r = m0 + ti * 8;                 // 8-aligned -> j = s&7 == ii
    const int bb = t0r >> 11, tt0 = t0r & 2047;
    const int cc = tt0 >> 5, lgs = (tt0 & 31) >> 3;
#pragma unroll
    for (int jj = 0; jj < 8; ++jj) {
      const int c = (n0 & 511) + tj * 8 + jj;
      const int h = c >> 6, dd = c & 63;
      bf8 pv;
#pragma unroll
      for (int ii = 0; ii < 8; ++ii) pv[ii] = f2bf(accL[ii][jj]);
      *reinterpret_cast<bf8*>(VF + (size_t)(bb * 8 + h) * 131072 +
                              cc * 2048 + (dd >> 4) * 512 +
                              ((dd & 15) + 16 * lgs) * 8) = pv;
    }
  }
}

// ------------------------------------------------------------- K3: out proj GEMM
__global__ __launch_bounds__(256) void out_mfma(
    const short* __restrict__ HOS, const short* __restrict__ WoS,
    float* __restrict__ OUT) {
  __shared__ short As[2][128][40];
  __shared__ short Bs[2][128][40];
  const int t = threadIdx.x;
  const int w = t >> 6, lane = t & 63;
  const int lq = lane & 15, lg = lane >> 4;
  const int wr = w >> 1, wc = w & 1;
  const int n0 = blockIdx.x * 128, m0 = blockIdx.y * 128;
  f32x4 acc[4][4];
#pragma unroll
  for (int i = 0; i < 4; ++i)
#pragma unroll
    for (int j2 = 0; j2 < 4; ++j2) acc[i][j2] = (f32x4){0.f, 0.f, 0.f, 0.f};
  const int sm = t >> 1, sh = (t & 1) * 16;
  for (int k0 = 0; k0 < 512; k0 += 32) {
#pragma unroll
    for (int lev = 0; lev < 2; ++lev) {
      const size_t xa = (size_t)lev * 4194304 + (size_t)(m0 + sm) * 512 + k0 + sh;
      *reinterpret_cast<bf8*>(&As[lev][sm][sh])     = *reinterpret_cast<const bf8*>(HOS + xa);
      *reinterpret_cast<bf8*>(&As[lev][sm][sh + 8]) = *reinterpret_cast<const bf8*>(HOS + xa + 8);
      const size_t wa = (size_t)lev * 262144 + (size_t)(n0 + sm) * 512 + k0 + sh;
      *reinterpret_cast<bf8*>(&Bs[lev][sm][sh])     = *reinterpret_cast<const bf8*>(WoS + wa);
      *reinterpret_cast<bf8*>(&Bs[lev][sm][sh + 8]) = *reinterpret_cast<const bf8*>(WoS + wa + 8);
    }
    __syncthreads();
    bf8 af[4][2], bfr[4][2];
#pragma unroll
    for (int i = 0; i < 4; ++i)
#pragma unroll
      for (int lev = 0; lev < 2; ++lev) {
        af[i][lev]  = *reinterpret_cast<const bf8*>(&As[lev][wr * 64 + i * 16 + lq][lg * 8]);
        bfr[i][lev] = *reinterpret_cast<const bf8*>(&Bs[lev][wc * 64 + i * 16 + lq][lg * 8]);
      }
#pragma unroll
    for (int mi = 0; mi < 4; ++mi)
#pragma unroll
      for (int ni = 0; ni < 4; ++ni) {
        MFMA16(af[mi][0], bfr[ni][0], acc[mi][ni]);
        MFMA16(af[mi][0], bfr[ni][1], acc[mi][ni]);
        MFMA16(af[mi][1], bfr[ni][0], acc[mi][ni]);
      }
    __syncthreads();
  }
#pragma unroll
  for (int mi = 0; mi < 4; ++mi)
#pragma unroll
    for (int r = 0; r < 4; ++r) {
      const int m = m0 + wr * 64 + mi * 16 + lg * 4 + r;
#pragma unroll
      for (int ni = 0; ni < 4; ++ni)
        OUT[(size_t)m * 512 + n0 + wc * 64 + ni * 16 + lq] = acc[mi][ni][r];
    }
}

// ---------------------------------------------------------------- K2: attention
// 512 threads = 8 waves; 8 q-rows/block; 64 KB LDS -> 2 blocks/CU.
// Lanes lq>=8 duplicate rows 0-7 (row = lq&7): same-address/same-value LDS
// writes in P1, duplicate (discarded) MFMA rows in P3.
__global__ __launch_bounds__(512, 4) void attn_mfma(
    const float* __restrict__ Qf32, const short* __restrict__ KF,
    const short* __restrict__ VF, const float* __restrict__ alpha,
    short* __restrict__ HOS) {
  extern __shared__ char lds[];
  const int tid = threadIdx.x;
  const int w = tid >> 6, lane = tid & 63;      // w in [0,8)
  const int lq = lane & 15, lg = lane >> 4;
  const int row = lq & 7;

  // XCD swizzle: 8192 blocks, 1024/XCD = 4 bh x 256 qb
  const int flat = blockIdx.x + (int)gridDim.x * blockIdx.y;
  const int xcd = flat & 7, idx = flat >> 3;
  const int bh = xcd * 4 + (idx >> 8);
  const int qb = idx & 255;
  const int b = bh >> 3, h = bh & 7;
  const int q0 = qb * 8;

  const float gate = 1.0f / (1.0f + __expf(-alpha[h]));
  const int key = row;                           // row's swizzle key (row < 8)

  // Q fragments: load f32 row q0+row, split 3-level in-register
  bf8 qf[3][2];
  {
    const float* qp = Qf32 + (size_t)bh * 131072 + (size_t)(q0 + row) * 64 + lg * 8;
#pragma unroll
    for (int kk = 0; kk < 2; ++kk) {
      const float4 g0 = *reinterpret_cast<const float4*>(qp + kk * 32);
      const float4 g1 = *reinterpret_cast<const float4*>(qp + kk * 32 + 4);
      const float v[8] = {g0.x, g0.y, g0.z, g0.w, g1.x, g1.y, g1.z, g1.w};
#pragma unroll
      for (int e = 0; e < 8; ++e) {
        const short s1 = f2bf(v[e]);  const float r1 = v[e] - bf2f(s1);
        const short s2 = f2bf(r1);
        const short s3 = f2bf(r1 - bf2f(s2));
        qf[0][kk][e] = s1; qf[1][kk][e] = s2; qf[2][kk][e] = s3;
      }
    }
  }

  auto ldk = [&](int t, bf8 (&dst)[3][2]) {
    const short* p = KF + (size_t)(bh * 128 + t) * 3072 + lane * 8;
    dst[0][0] = *reinterpret_cast<const bf8*>(p);
    dst[0][1] = *reinterpret_cast<const bf8*>(p + 512);
    dst[1][0] = *reinterpret_cast<const bf8*>(p + 1024);
    dst[1][1] = *reinterpret_cast<const bf8*>(p + 1536);
    dst[2][0] = *reinterpret_cast<const bf8*>(p + 2048);
    dst[2][1] = *reinterpret_cast<const bf8*>(p + 2560);
  };
  auto qk = [&](bf8 (&kf)[3][2], int t) {
    f32x4 c0 = {0.f,0.f,0.f,0.f}, c1 = {0.f,0.f,0.f,0.f}, c2 = {0.f,0.f,0.f,0.f};
#pragma unroll
    for (int kk = 0; kk < 2; ++kk) {
      MFMA16(kf[0][kk], qf[0][kk], c0);   // 1
      MFMA16(kf[0][kk], qf[1][kk], c1);   // 2^-8
      MFMA16(kf[1][kk], qf[0][kk], c1);   // 2^-8
      MFMA16(kf[1][kk], qf[1][kk], c2);   // 2^-16
      MFMA16(kf[0][kk], qf[2][kk], c2);   // 2^-16
      MFMA16(kf[2][kk], qf[0][kk], c2);   // 2^-16
    }
    const f32x4 c = (c0 + c1) + c2;
    // lanes lq>=8 write the same address+value as their lq-8 twin (benign)
    *reinterpret_cast<f32x4*>(
        lds + row * 8192 + ((((t << 2) + lg) ^ key) << 4)) = c;
  };

  // ---- P1: logits (double-buffered, 16 tiles/wave)
  {
    bf8 ka[3][2], kb[3][2];
    ldk(w, ka);
#pragma unroll
    for (int j = 0; j < 16; j += 2) {
      const int t0 = w + 8 * j;
      ldk(t0 + 8, kb);
      qk(ka, t0);
      if (j + 2 < 16) ldk(t0 + 16, ka);
      qk(kb, t0 + 8);
    }
  }
  __syncthreads();

  // V prefetch for P3 chunk w (latency hidden under P2)
  bf8 va[4], vb[4];
  auto ldv = [&](int cc, bf8 (&dst)[4]) {
    const short* p = VF + (size_t)(bh * 64 + cc) * 2048 + lane * 8;
    dst[0] = *reinterpret_cast<const bf8*>(p);
    dst[1] = *reinterpret_cast<const bf8*>(p + 512);
    dst[2] = *reinterpret_cast<const bf8*>(p + 1024);
    dst[3] = *reinterpret_cast<const bf8*>(p + 1536);
  };
  ldv(w, va);

  // ---- P2: wave w owns row q=w. Float-space top-64 threshold: value-space
  // bisection with ballot/popcount counts; the common exit is cnt==64 (probe
  // landed in the (v65, v64] gap). Adjacent-float brackets converge to
  // lo == v64 exactly; bit-duplicate ties select >=64 same as the R9 search.
  {
    const int q = w;
    const int rkey = q & 7;
    const char* rowb = lds + q * 8192;
    float av[32];
    float lm = -3.402823466e+38f;
#pragma unroll
    for (int jj = 0; jj < 8; ++jj) {
      const f32x4 v = *reinterpret_cast<const f32x4*>(rowb + ((lane + 64 * jj) << 4));
#pragma unroll
      for (int e = 0; e < 4; ++e) {
        av[jj * 4 + e] = v[e];
        lm = fmaxf(lm, v[e]);
      }
    }
    // m = global max; g0 = min of per-lane maxima -> cnt(>=g0) >= 64.
    float m = lm, g0 = lm;
#pragma unroll
    for (int off = 32; off; off >>= 1) m = fmaxf(m, __shfl_xor(m, off));
#pragma unroll
    for (int off = 32; off; off >>= 1) g0 = fminf(g0, __shfl_xor(g0, off));
    float ev[32]; float dsum = 0.f;
#pragma unroll
    for (int j = 0; j < 32; ++j) {
      ev[j] = __expf(av[j] - m);
      dsum += ev[j];
    }
#pragma unroll
    for (int off = 32; off; off >>= 1) dsum += __shfl_xor(dsum, off);
    // invariant: cnt(>= lo) >= 64; cnt(>= hi) < 64 (generic case)
    float lo = g0, hi = m;
    for (int it = 0; it < 64; ++it) {
      const float mid = 0.5f * (lo + hi);
      if (!(mid > lo && mid < hi)) break;      // bracket collapsed (ties)
      int cnt = 0;
#pragma unroll
      for (int j = 0; j < 32; ++j)
        cnt += (int)__popcll(__ballot(av[j] >= mid));
      if (cnt >= 64) {
        lo = mid;
        if (cnt == 64) break;                  // gap hit: set is exactly top-64
      } else {
        hi = mid;
      }
    }
    const float thr = lo;
    float ssum = 0.f;
#pragma unroll
    for (int j = 0; j < 32; ++j) ssum += (av[j] >= thr) ? ev[j] : 0.f;
#pragma unroll
    for (int off = 32; off; off >>= 1) ssum += __shfl_xor(ssum, off);
    const float dinv = gate / dsum;
    const float sinv = (1.0f - gate) / ssum;
#pragma unroll
    for (int jj = 0; jj < 8; ++jj) {
      const int p = lane + 64 * jj;
      const int f = p ^ rkey;
      const float w0 = ev[jj*4+0] * (dinv + ((av[jj*4+0] >= thr) ? sinv : 0.f));
      const float w1 = ev[jj*4+1] * (dinv + ((av[jj*4+1] >= thr) ? sinv : 0.f));
      const float w2 = ev[jj*4+2] * (dinv + ((av[jj*4+2] >= thr) ? sinv : 0.f));
      const float w3 = ev[jj*4+3] * (dinv + ((av[jj*4+3] >= thr) ? sinv : 0.f));
      uint2 pk;
      pk.x = pack_bf16x2(w0, w1);
      pk.y = pack_bf16x2(w2, w3);
      *reinterpret_cast<uint2*>(
          lds + q * 8192 + ((((f >> 1) ^ rkey) << 4) + ((f & 1) << 3))) = pk;
    }
  }
  __syncthreads();

  // ---- P3: PV. wave w does s-chunks cc = w + 8j (8 chunks of 32 s), 4 d-tiles.
  f32x4 o0 = {0.f,0.f,0.f,0.f}, o1 = {0.f,0.f,0.f,0.f};
  f32x4 o2 = {0.f,0.f,0.f,0.f}, o3 = {0.f,0.f,0.f,0.f};
  {
    auto pv = [&](bf8 (&vv)[4], int cc) {
      const bf8 pa = *reinterpret_cast<const bf8*>(
          lds + row * 8192 + ((((cc << 2) + lg) ^ key) << 4));
      MFMA16(pa, vv[0], o0);
      MFMA16(pa, vv[1], o1);
      MFMA16(pa, vv[2], o2);
      MFMA16(pa, vv[3], o3);
    };
#pragma unroll
    for (int j = 0; j < 8; j += 2) {
      const int cc = w + 8 * j;
      ldv(cc + 8, vb);
      pv(va, cc);
      if (j + 2 < 8) ldv(cc + 16, va);
      pv(vb, cc + 8);
    }
  }
  // park partials: tile = w*4+dt in [0,32): row tile&7, slot tile>>3
  {
    const f32x4 oo[4] = {o0, o1, o2, o3};
#pragma unroll
    for (int dt = 0; dt < 4; ++dt) {
      const int tile = w * 4 + dt;
      char* pb = lds + (tile & 7) * 8192 + 4096 + ((tile >> 3) << 10);
#pragma unroll
      for (int r = 0; r < 4; ++r)
        *reinterpret_cast<float*>(pb + (((lg * 4 + r) * 16 + lq) << 2)) = oo[dt][r];
    }
  }
  __syncthreads();
  // reduce 8 wave-partials, write HOS (2-level bf16). 512 thr = 8 q x 64 d.
  {
    const int q = tid >> 6, d = tid & 63;
    const int dt = d >> 4;
    float s = 0.f;
#pragma unroll
    for (int ww = 0; ww < 8; ++ww) {
      const int tile = ww * 4 + dt;
      s += *reinterpret_cast<const float*>(
          lds + (tile & 7) * 8192 + 4096 + ((tile >> 3) << 10) +
          ((q * 16 + (d & 15)) << 2));
    }
    const size_t o = (size_t)(b * TSEQ + q0 + q) * 512 + h * 64 + d;
    const short s1 = f2bf(s);
    HOS[o] = s1;
    HOS[o + 4194304] = f2bf(s - bf2f(s1));
  }
}

// ------------------------------------------------------------------- launcher
extern "C" void kernel_launch(void* const* d_in, const int* in_sizes, int n_in,
                              void* d_out, int out_size, void* d_ws, size_t ws_size,
                              hipStream_t stream) {
  const float* x     = (const float*)d_in[0];
  const float* Wqkv  = (const float*)d_in[1];
  const float* Wout  = (const float*)d_in[2];
  const float* alpha = (const float*)d_in[3];
  float* out = (float*)d_out;

  float* Qf32 = (float*)d_ws;
  short* S16  = (short*)d_ws;
  short* KF   = S16 + 8388608;
  short* VF   = S16 + 20971520;
  short* HOS  = S16 + 25165824;
  short* WoS  = S16 + 33554432;
  short* WqS  = S16 + 34078720;   // 3 x 1536 x 512
  short* XSp  = S16 + 36438016;   // 3 x 8192 x 512

  const int attn_lds = 65536;
  (void)hipFuncSetAttribute((const void*)attn_mfma,
                            hipFuncAttributeMaxDynamicSharedMemorySize, attn_lds);

  transpose_split<<<dim3(4, 16), 256, 0, stream>>>(Wout, WoS, 512, 512);

  const bool big = ws_size >= (size_t)98041856;
  if (big) {
    transpose_split3<<<dim3(12, 16), 256, 0, stream>>>(Wqkv, WqS, 512, 1536);
    xsplit3<<<2048, 256, 0, stream>>>(x, XSp);
    const int qkv_lds = 67584;
    (void)hipFuncSetAttribute((const void*)qkv_mfma,
                              hipFuncAttributeMaxDynamicSharedMemorySize, qkv_lds);
    qkv_mfma<<<dim3(12, 64), 256, qkv_lds, stream>>>(XSp, WqS, Qf32, KF, VF);
  } else {
    qkv_gemm<<<dim3(12, 64), 256, 0, stream>>>(x, Wqkv, Qf32, KF, VF);
  }
  attn_mfma<<<dim3(256, 32), 512, attn_lds, stream>>>(Qf32, KF, VF, alpha, HOS);
  out_mfma<<<dim3(4, 64), 256, 0, stream>>>(HOS, WoS, out);
}

// Round 5
// 470.407 us; speedup vs baseline: 3.2499x; 1.0488x over previous
//
#include <hip/hip_runtime.h>
#include <hip/hip_bf16.h>
#include <cstdint>
#include <cstddef>

// AdaptiveSparseSelfAttention — round 13: attn re-tiled to 16 DISTINCT q-rows
// per block (1024 thr / 16 waves / 128 KB LDS / 1 block/CU). row = lq kills
// the lq>=8 duplication: every MFMA row useful -> P1+P3 MFMA issue halves,
// K/V L2 traffic halves (128 blocks/bh vs 256), P1-epilogue VALU halves.
// P2 selection code is VERBATIM R12 (wave w owns row q=w, q now in [0,16)).
// Park uses the same 4KB/row spare (64 tiles -> (tile&15, tile>>4) slots);
// reduce sums 16 partials. Same 3 barriers. Logits bit-identical to R12.
// Rationale: prior session's 16-row loss predates the slim P2 (R9 ballot +
// R12 float-bisect); with P2 3x slimmer the 2-block overlap matters less
// than halving MFMA.
//
// ws layout (98,041,856 B total when big path active):
//   Qf32 f32  [32][2048][64]                4,194,304 f  @ short 0
//   KF   bf16 [32][128 kt][3][2][64][8]    12,582,912 s  @ short 8,388,608
//   VF   bf16 [32][64 cc][4 dt][64][8]      4,194,304 s  @ short 20,971,520
//   HOS  bf16 [2 lev][8192][512]            8,388,608 s  @ short 25,165,824
//   WoS  bf16 [2 lev][512][512]               524,288 s  @ short 33,554,432
//   WqS  bf16 [3 lev][1536][512]            2,359,296 s  @ short 34,078,720
//   XS   bf16 [3 lev][8192][512]           12,582,912 s  @ short 36,438,016

#define TSEQ 2048

typedef __attribute__((ext_vector_type(8))) short bf8;
typedef __attribute__((ext_vector_type(4))) float f32x4;

#define MFMA16(A, B, C) \
  C = __builtin_amdgcn_mfma_f32_16x16x32_bf16(A, B, C, 0, 0, 0)

static __device__ __forceinline__ short f2bf(float f) {
  unsigned u = __float_as_uint(f);
  u += 0x7FFFu + ((u >> 16) & 1u);
  return (short)(u >> 16);
}
static __device__ __forceinline__ float bf2f(short s) {
  return __uint_as_float(((unsigned)(unsigned short)s) << 16);
}
static __device__ __forceinline__ unsigned pack_bf16x2(float a, float b) {
  float2 f2; f2.x = a; f2.y = b;
  __hip_bfloat162 h = __float22bfloat162_rn(f2);   // RNE, same bits as f2bf
  unsigned r;
  __builtin_memcpy(&r, &h, 4);
  return r;
}

// ---------------------------------------- prep: transpose + split weight matrix
// W[K][N] -> out[lev][N][K], lev stride N*K (2 levels, for Wout)
__global__ __launch_bounds__(256) void transpose_split(
    const float* __restrict__ W, short* __restrict__ out, int K, int N) {
  __shared__ float tile[32][129];
  const int t = threadIdx.x;
  const int nb = blockIdx.x * 128, kb = blockIdx.y * 32;
#pragma unroll
  for (int c = 0; c < 4; ++c) {
    const int flat = c * 256 + t;
    const int r = flat >> 5, nq = (flat & 31) * 4;
    const float4 g = *reinterpret_cast<const float4*>(&W[(size_t)(kb + r) * N + nb + nq]);
    tile[r][nq] = g.x; tile[r][nq + 1] = g.y;
    tile[r][nq + 2] = g.z; tile[r][nq + 3] = g.w;
  }
  __syncthreads();
  const int n = t >> 1, kh = (t & 1) * 16;
  bf8 a0, a1, b0, b1;
#pragma unroll
  for (int e = 0; e < 16; ++e) {
    const float f = tile[kh + e][n];
    const short s1 = f2bf(f);
    const short s2 = f2bf(f - bf2f(s1));
    if (e < 8) { a0[e] = s1; b0[e] = s2; }
    else       { a1[e - 8] = s1; b1[e - 8] = s2; }
  }
  const size_t o = (size_t)(nb + n) * K + kb + kh;
  const size_t ls = (size_t)N * K;
  *reinterpret_cast<bf8*>(out + o) = a0;
  *reinterpret_cast<bf8*>(out + o + 8) = a1;
  *reinterpret_cast<bf8*>(out + o + ls) = b0;
  *reinterpret_cast<bf8*>(out + o + ls + 8) = b1;
}

// 3-level variant (for Wqkv): W[K][N] -> out[lev][N][K], lev stride N*K
__global__ __launch_bounds__(256) void transpose_split3(
    const float* __restrict__ W, short* __restrict__ out, int K, int N) {
  __shared__ float tile[32][129];
  const int t = threadIdx.x;
  const int nb = blockIdx.x * 128, kb = blockIdx.y * 32;
#pragma unroll
  for (int c = 0; c < 4; ++c) {
    const int flat = c * 256 + t;
    const int r = flat >> 5, nq = (flat & 31) * 4;
    const float4 g = *reinterpret_cast<const float4*>(&W[(size_t)(kb + r) * N + nb + nq]);
    tile[r][nq] = g.x; tile[r][nq + 1] = g.y;
    tile[r][nq + 2] = g.z; tile[r][nq + 3] = g.w;
  }
  __syncthreads();
  const int n = t >> 1, kh = (t & 1) * 16;
  bf8 a0, a1, b0, b1, c0, c1;
#pragma unroll
  for (int e = 0; e < 16; ++e) {
    const float f = tile[kh + e][n];
    const short s1 = f2bf(f);  const float r1 = f - bf2f(s1);
    const short s2 = f2bf(r1);
    const short s3 = f2bf(r1 - bf2f(s2));
    if (e < 8) { a0[e] = s1; b0[e] = s2; c0[e] = s3; }
    else       { a1[e - 8] = s1; b1[e - 8] = s2; c1[e - 8] = s3; }
  }
  const size_t o = (size_t)(nb + n) * K + kb + kh;
  const size_t ls = (size_t)N * K;
  *reinterpret_cast<bf8*>(out + o) = a0;
  *reinterpret_cast<bf8*>(out + o + 8) = a1;
  *reinterpret_cast<bf8*>(out + o + ls) = b0;
  *reinterpret_cast<bf8*>(out + o + ls + 8) = b1;
  *reinterpret_cast<bf8*>(out + o + 2 * ls) = c0;
  *reinterpret_cast<bf8*>(out + o + 2 * ls + 8) = c1;
}

// prep: X[8192][512] f32 -> XS[3][8192][512] bf16 (3-level split, row-major)
__global__ __launch_bounds__(256) void xsplit3(
    const float* __restrict__ X, short* __restrict__ XS) {
  const int i = (blockIdx.x * 256 + threadIdx.x) * 8;
  const float4 g0 = *reinterpret_cast<const float4*>(X + i);
  const float4 g1 = *reinterpret_cast<const float4*>(X + i + 4);
  const float v[8] = {g0.x, g0.y, g0.z, g0.w, g1.x, g1.y, g1.z, g1.w};
  bf8 s1v, s2v, s3v;
#pragma unroll
  for (int e = 0; e < 8; ++e) {
    const short s1 = f2bf(v[e]);  const float r1 = v[e] - bf2f(s1);
    const short s2 = f2bf(r1);
    const short s3 = f2bf(r1 - bf2f(s2));
    s1v[e] = s1; s2v[e] = s2; s3v[e] = s3;
  }
  *reinterpret_cast<bf8*>(XS + i)           = s1v;
  *reinterpret_cast<bf8*>(XS + i + 4194304) = s2v;
  *reinterpret_cast<bf8*>(XS + i + 8388608) = s3v;
}

// ---------------------------------------------------------------- K1: qkv GEMM
// Fallback path: f32 VALU (R4-proven numerics).
__global__ __launch_bounds__(256) void qkv_gemm(
    const float* __restrict__ X, const float* __restrict__ W,
    float* __restrict__ Qf32, short* __restrict__ KF, short* __restrict__ VF) {
  __shared__ float As[16][132];
  __shared__ float Bs[16][132];
  const int t = threadIdx.x;
  const int n0 = blockIdx.x * 128;
  const int m0 = blockIdx.y * 128;
  const int ti = t >> 4, tj = t & 15;
  float acc[8][8] = {};
  for (int kt = 0; kt < 512; kt += 16) {
#pragma unroll
    for (int e = 0; e < 2; ++e) {
      int idx = e * 256 + t;
      int m = idx >> 2, kq = (idx & 3) << 2;
      const float4 g = *reinterpret_cast<const float4*>(
          &X[(size_t)(m0 + m) * 512 + kt + kq]);
      As[kq + 0][m] = g.x; As[kq + 1][m] = g.y;
      As[kq + 2][m] = g.z; As[kq + 3][m] = g.w;
    }
#pragma unroll
    for (int e = 0; e < 2; ++e) {
      int idx = e * 256 + t;
      int kk = idx >> 5, n4 = (idx & 31) << 2;
      *reinterpret_cast<float4*>(&Bs[kk][n4]) =
          *reinterpret_cast<const float4*>(&W[(size_t)(kt + kk) * 1536 + n0 + n4]);
    }
    __syncthreads();
#pragma unroll
    for (int kk = 0; kk < 16; ++kk) {
      const float4 A0 = *reinterpret_cast<const float4*>(&As[kk][ti * 8]);
      const float4 A1 = *reinterpret_cast<const float4*>(&As[kk][ti * 8 + 4]);
      const float4 B0 = *reinterpret_cast<const float4*>(&Bs[kk][tj * 8]);
      const float4 B1 = *reinterpret_cast<const float4*>(&Bs[kk][tj * 8 + 4]);
      const float a[8] = {A0.x, A0.y, A0.z, A0.w, A1.x, A1.y, A1.z, A1.w};
      const float b[8] = {B0.x, B0.y, B0.z, B0.w, B1.x, B1.y, B1.z, B1.w};
#pragma unroll
      for (int ii = 0; ii < 8; ++ii)
#pragma unroll
        for (int jj = 0; jj < 8; ++jj)
          acc[ii][jj] = fmaf(a[ii], b[jj], acc[ii][jj]);
    }
    __syncthreads();
  }
  const int part = n0 >> 9;     // 0=Q 1=K 2=V
  if (part == 0) {
#pragma unroll
    for (int ii = 0; ii < 8; ++ii) {
      const int r = m0 + ti * 8 + ii;
      const int bb = r >> 11, tt = r & 2047;
#pragma unroll
      for (int jj = 0; jj < 8; ++jj) {
        const int c = (n0 & 511) + tj * 8 + jj;
        const int h = c >> 6, d = c & 63;
        Qf32[(size_t)(bb * 8 + h) * 131072 + (size_t)tt * 64 + d] =
            acc[ii][jj] * 0.125f;
      }
    }
  } else if (part == 1) {
    const int cc0 = (n0 & 511) + tj * 8;
    const int h = cc0 >> 6, d0 = cc0 & 63;
    const int kk = d0 >> 5, lg = (d0 & 31) >> 3;   // j = d&7 == jj
#pragma unroll
    for (int ii = 0; ii < 8; ++ii) {
      const int r = m0 + ti * 8 + ii;
      const int bb = r >> 11, tt = r & 2047;
      const size_t base = (size_t)(bb * 8 + h) * 393216 +
                          (size_t)(tt >> 4) * 3072 + kk * 512 +
                          ((tt & 15) + 16 * lg) * 8;
      bf8 v1, v2, v3;
#pragma unroll
      for (int jj = 0; jj < 8; ++jj) {
        const float f = acc[ii][jj];
        const short s1 = f2bf(f);  const float r1 = f - bf2f(s1);
        const short s2 = f2bf(r1);
        const short s3 = f2bf(r1 - bf2f(s2));
        v1[jj] = s1; v2[jj] = s2; v3[jj] = s3;
      }
      *reinterpret_cast<bf8*>(KF + base)        = v1;
      *reinterpret_cast<bf8*>(KF + base + 1024) = v2;
      *reinterpret_cast<bf8*>(KF + base + 2048) = v3;
    }
  } else {
    const int t0r = m0 + ti * 8;                 // 8-aligned -> j = s&7 == ii
    const int bb = t0r >> 11, tt0 = t0r & 2047;
    const int cc = tt0 >> 5, lgs = (tt0 & 31) >> 3;
#pragma unroll
    for (int jj = 0; jj < 8; ++jj) {
      const int c = (n0 & 511) + tj * 8 + jj;
      const int h = c >> 6, dd = c & 63;
      bf8 pv;
#pragma unroll
      for (int ii = 0; ii < 8; ++ii) pv[ii] = f2bf(acc[ii][jj]);
      *reinterpret_cast<bf8*>(VF + (size_t)(bb * 8 + h) * 131072 +
                              cc * 2048 + (dd >> 4) * 512 +
                              ((dd & 15) + 16 * lgs) * 8) = pv;
    }
  }
}

// ---------------------------------------- K1': qkv GEMM via MFMA (main path)
// A = XS [3][8192][512], B = WqS [3][1536][512]; 6-term ladder, LV=3 STATIC
// for all parts (compile-time indexing only — no runtime-bound lev loops).
// Accs round-trip through LDS scratch so the proven (ti,tj) epilogue is reused.
__global__ __launch_bounds__(256) void qkv_mfma(
    const short* __restrict__ XS, const short* __restrict__ WqS,
    float* __restrict__ Qf32, short* __restrict__ KF, short* __restrict__ VF) {
  extern __shared__ char sm_[];
  short* As = (short*)sm_;                 // [3][128][40] bf16
  short* Bs = (short*)(sm_ + 30720);       // [3][128][40] bf16
  float* SC = (float*)sm_;                 // [128][132] f32 (after k-loop)
  const int t = threadIdx.x;
  const int w = t >> 6, lane = t & 63;
  const int lq = lane & 15, lg = lane >> 4;
  const int wr = w >> 1, wc = w & 1;
  const int n0 = blockIdx.x * 128, m0 = blockIdx.y * 128;
  const int part = n0 >> 9;                // 0=Q 1=K 2=V
  f32x4 acc[4][4];
#pragma unroll
  for (int i = 0; i < 4; ++i)
#pragma unroll
    for (int j2 = 0; j2 < 4; ++j2) acc[i][j2] = (f32x4){0.f, 0.f, 0.f, 0.f};
  const int sr = t >> 1, sh = (t & 1) * 16;
  for (int k0 = 0; k0 < 512; k0 += 32) {
#pragma unroll
    for (int lev = 0; lev < 3; ++lev) {
      const size_t xa = (size_t)lev * 4194304 + (size_t)(m0 + sr) * 512 + k0 + sh;
      *reinterpret_cast<bf8*>(&As[(lev * 128 + sr) * 40 + sh])     =
          *reinterpret_cast<const bf8*>(XS + xa);
      *reinterpret_cast<bf8*>(&As[(lev * 128 + sr) * 40 + sh + 8]) =
          *reinterpret_cast<const bf8*>(XS + xa + 8);
      const size_t wa = (size_t)lev * 786432 + (size_t)(n0 + sr) * 512 + k0 + sh;
      *reinterpret_cast<bf8*>(&Bs[(lev * 128 + sr) * 40 + sh])     =
          *reinterpret_cast<const bf8*>(WqS + wa);
      *reinterpret_cast<bf8*>(&Bs[(lev * 128 + sr) * 40 + sh + 8]) =
          *reinterpret_cast<const bf8*>(WqS + wa + 8);
    }
    __syncthreads();
    bf8 bfr[4][3];
#pragma unroll
    for (int i = 0; i < 4; ++i)
#pragma unroll
      for (int lev = 0; lev < 3; ++lev)
        bfr[i][lev] = *reinterpret_cast<const bf8*>(
            &Bs[(lev * 128 + wc * 64 + i * 16 + lq) * 40 + lg * 8]);
#pragma unroll
    for (int mi = 0; mi < 4; ++mi) {
      bf8 af0 = *reinterpret_cast<const bf8*>(
          &As[(0 * 128 + wr * 64 + mi * 16 + lq) * 40 + lg * 8]);
      bf8 af1 = *reinterpret_cast<const bf8*>(
          &As[(1 * 128 + wr * 64 + mi * 16 + lq) * 40 + lg * 8]);
      bf8 af2 = *reinterpret_cast<const bf8*>(
          &As[(2 * 128 + wr * 64 + mi * 16 + lq) * 40 + lg * 8]);
#pragma unroll
      for (int ni = 0; ni < 4; ++ni) {
        MFMA16(af0, bfr[ni][0], acc[mi][ni]);       // 1
        MFMA16(af0, bfr[ni][1], acc[mi][ni]);       // 2^-8
        MFMA16(af1, bfr[ni][0], acc[mi][ni]);       // 2^-8
        MFMA16(af1, bfr[ni][1], acc[mi][ni]);       // 2^-16
        MFMA16(af0, bfr[ni][2], acc[mi][ni]);       // 2^-16
        MFMA16(af2, bfr[ni][0], acc[mi][ni]);       // 2^-16
      }
    }
    __syncthreads();
  }
  // dump accs to scratch in (m,n) order
#pragma unroll
  for (int mi = 0; mi < 4; ++mi)
#pragma unroll
    for (int ni = 0; ni < 4; ++ni)
#pragma unroll
      for (int r = 0; r < 4; ++r)
        SC[(wr * 64 + mi * 16 + lg * 4 + r) * 132 + wc * 64 + ni * 16 + lq] =
            acc[mi][ni][r];
  __syncthreads();
  // epilogue: verbatim qkv_gemm scatter, accL re-read in (ti,tj) 8x8 order
  const int ti = t >> 4, tj = t & 15;
  float accL[8][8];
#pragma unroll
  for (int ii = 0; ii < 8; ++ii) {
    const float4 c0 = *reinterpret_cast<const float4*>(&SC[(ti * 8 + ii) * 132 + tj * 8]);
    const float4 c1 = *reinterpret_cast<const float4*>(&SC[(ti * 8 + ii) * 132 + tj * 8 + 4]);
    accL[ii][0] = c0.x; accL[ii][1] = c0.y; accL[ii][2] = c0.z; accL[ii][3] = c0.w;
    accL[ii][4] = c1.x; accL[ii][5] = c1.y; accL[ii][6] = c1.z; accL[ii][7] = c1.w;
  }
  if (part == 0) {
#pragma unroll
    for (int ii = 0; ii < 8; ++ii) {
      const int r = m0 + ti * 8 + ii;
      const int bb = r >> 11, tt = r & 2047;
#pragma unroll
      for (int jj = 0; jj < 8; ++jj) {
        const int c = (n0 & 511) + tj * 8 + jj;
        const int h = c >> 6, d = c & 63;
        Qf32[(size_t)(bb * 8 + h) * 131072 + (size_t)tt * 64 + d] =
            accL[ii][jj] * 0.125f;
      }
    }
  } else if (part == 1) {
    const int cc0 = (n0 & 511) + tj * 8;
    const int h = cc0 >> 6, d0 = cc0 & 63;
    const int kk = d0 >> 5, lg2 = (d0 & 31) >> 3;   // j = d&7 == jj
#pragma unroll
    for (int ii = 0; ii < 8; ++ii) {
      const int r = m0 + ti * 8 + ii;
      const int bb = r >> 11, tt = r & 2047;
      const size_t base = (size_t)(bb * 8 + h) * 393216 +
                          (size_t)(tt >> 4) * 3072 + kk * 512 +
                          ((tt & 15) + 16 * lg2) * 8;
      bf8 v1, v2, v3;
#pragma unroll
      for (int jj = 0; jj < 8; ++jj) {
        const float f = accL[ii][jj];
        const short s1 = f2bf(f);  const float r1 = f - bf2f(s1);
        const short s2 = f2bf(r1);
        const short s3 = f2bf(r1 - bf2f(s2));
        v1[jj] = s1; v2[jj] = s2; v3[jj] = s3;
      }
      *reinterpret_cast<bf8*>(KF + base)        = v1;
      *reinterpret_cast<bf8*>(KF + base + 1024) = v2;
      *reinterpret_cast<bf8*>(KF + base + 2048) = v3;
    }
  } else {
    const int t0r = m0 + ti * 8;                 // 8-aligned -> j = s&7 == ii
    const int bb = t0r >> 11, tt0 = t0r & 2047;
    const int cc = tt0 >> 5, lgs = (tt0 & 31) >> 3;
#pragma unroll
    for (int jj = 0; jj < 8; ++jj) {
      const int c = (n0 & 511) + tj * 8 + jj;
      const int h = c >> 6, dd = c & 63;
      bf8 pv;
#pragma unroll
      for (int ii = 0; ii < 8; ++ii) pv[ii] = f2bf(accL[ii][jj]);
      *reinterpret_cast<bf8*>(VF + (size_t)(bb * 8 + h) * 131072 +
                              cc * 2048 + (dd >> 4) * 512 +
                              ((dd & 15) + 16 * lgs) * 8) = pv;
    }
  }
}

// ------------------------------------------------------------- K3: out proj GEMM
__global__ __launch_bounds__(256) void out_mfma(
    const short* __restrict__ HOS, const short* __restrict__ WoS,
    float* __restrict__ OUT) {
  __shared__ short As[2][128][40];
  __shared__ short Bs[2][128][40];
  const int t = threadIdx.x;
  const int w = t >> 6, lane = t & 63;
  const int lq = lane & 15, lg = lane >> 4;
  const int wr = w >> 1, wc = w & 1;
  const int n0 = blockIdx.x * 128, m0 = blockIdx.y * 128;
  f32x4 acc[4][4];
#pragma unroll
  for (int i = 0; i < 4; ++i)
#pragma unroll
    for (int j2 = 0; j2 < 4; ++j2) acc[i][j2] = (f32x4){0.f, 0.f, 0.f, 0.f};
  const int sm = t >> 1, sh = (t & 1) * 16;
  for (int k0 = 0; k0 < 512; k0 += 32) {
#pragma unroll
    for (int lev = 0; lev < 2; ++lev) {
      const size_t xa = (size_t)lev * 4194304 + (size_t)(m0 + sm) * 512 + k0 + sh;
      *reinterpret_cast<bf8*>(&As[lev][sm][sh])     = *reinterpret_cast<const bf8*>(HOS + xa);
      *reinterpret_cast<bf8*>(&As[lev][sm][sh + 8]) = *reinterpret_cast<const bf8*>(HOS + xa + 8);
      const size_t wa = (size_t)lev * 262144 + (size_t)(n0 + sm) * 512 + k0 + sh;
      *reinterpret_cast<bf8*>(&Bs[lev][sm][sh])     = *reinterpret_cast<const bf8*>(WoS + wa);
      *reinterpret_cast<bf8*>(&Bs[lev][sm][sh + 8]) = *reinterpret_cast<const bf8*>(WoS + wa + 8);
    }
    __syncthreads();
    bf8 af[4][2], bfr[4][2];
#pragma unroll
    for (int i = 0; i < 4; ++i)
#pragma unroll
      for (int lev = 0; lev < 2; ++lev) {
        af[i][lev]  = *reinterpret_cast<const bf8*>(&As[lev][wr * 64 + i * 16 + lq][lg * 8]);
        bfr[i][lev] = *reinterpret_cast<const bf8*>(&Bs[lev][wc * 64 + i * 16 + lq][lg * 8]);
      }
#pragma unroll
    for (int mi = 0; mi < 4; ++mi)
#pragma unroll
      for (int ni = 0; ni < 4; ++ni) {
        MFMA16(af[mi][0], bfr[ni][0], acc[mi][ni]);
        MFMA16(af[mi][0], bfr[ni][1], acc[mi][ni]);
        MFMA16(af[mi][1], bfr[ni][0], acc[mi][ni]);
      }
    __syncthreads();
  }
#pragma unroll
  for (int mi = 0; mi < 4; ++mi)
#pragma unroll
    for (int r = 0; r < 4; ++r) {
      const int m = m0 + wr * 64 + mi * 16 + lg * 4 + r;
#pragma unroll
      for (int ni = 0; ni < 4; ++ni)
        OUT[(size_t)m * 512 + n0 + wc * 64 + ni * 16 + lq] = acc[mi][ni][r];
    }
}

// ---------------------------------------------------------------- K2: attention
// 1024 threads = 16 waves; 16 DISTINCT q-rows/block (row = lq, no duplication);
// 128 KB LDS -> 1 block/CU, 16 waves/CU (same wave count as R12's 2x8).
__global__ __launch_bounds__(1024, 4) void attn_mfma(
    const float* __restrict__ Qf32, const short* __restrict__ KF,
    const short* __restrict__ VF, const float* __restrict__ alpha,
    short* __restrict__ HOS) {
  extern __shared__ char lds[];
  const int tid = threadIdx.x;
  const int w = tid >> 6, lane = tid & 63;      // w in [0,16)
  const int lq = lane & 15, lg = lane >> 4;
  const int row = lq;                            // 16 distinct rows

  // XCD swizzle: 4096 blocks, 512/XCD = 4 bh x 128 qb
  const int flat = blockIdx.x + (int)gridDim.x * blockIdx.y;
  const int xcd = flat & 7, idx = flat >> 3;
  const int bh = xcd * 4 + (idx >> 7);
  const int qb = idx & 127;
  const int b = bh >> 3, h = bh & 7;
  const int q0 = qb * 16;

  const float gate = 1.0f / (1.0f + __expf(-alpha[h]));
  const int key = row & 7;                       // row's swizzle key

  // Q fragments: load f32 row q0+row, split 3-level in-register
  bf8 qf[3][2];
  {
    const float* qp = Qf32 + (size_t)bh * 131072 + (size_t)(q0 + row) * 64 + lg * 8;
#pragma unroll
    for (int kk = 0; kk < 2; ++kk) {
      const float4 g0 = *reinterpret_cast<const float4*>(qp + kk * 32);
      const float4 g1 = *reinterpret_cast<const float4*>(qp + kk * 32 + 4);
      const float v[8] = {g0.x, g0.y, g0.z, g0.w, g1.x, g1.y, g1.z, g1.w};
#pragma unroll
      for (int e = 0; e < 8; ++e) {
        const short s1 = f2bf(v[e]);  const float r1 = v[e] - bf2f(s1);
        const short s2 = f2bf(r1);
        const short s3 = f2bf(r1 - bf2f(s2));
        qf[0][kk][e] = s1; qf[1][kk][e] = s2; qf[2][kk][e] = s3;
      }
    }
  }

  auto ldk = [&](int t, bf8 (&dst)[3][2]) {
    const short* p = KF + (size_t)(bh * 128 + t) * 3072 + lane * 8;
    dst[0][0] = *reinterpret_cast<const bf8*>(p);
    dst[0][1] = *reinterpret_cast<const bf8*>(p + 512);
    dst[1][0] = *reinterpret_cast<const bf8*>(p + 1024);
    dst[1][1] = *reinterpret_cast<const bf8*>(p + 1536);
    dst[2][0] = *reinterpret_cast<const bf8*>(p + 2048);
    dst[2][1] = *reinterpret_cast<const bf8*>(p + 2560);
  };
  auto qk = [&](bf8 (&kf)[3][2], int t) {
    f32x4 c0 = {0.f,0.f,0.f,0.f}, c1 = {0.f,0.f,0.f,0.f}, c2 = {0.f,0.f,0.f,0.f};
#pragma unroll
    for (int kk = 0; kk < 2; ++kk) {
      MFMA16(kf[0][kk], qf[0][kk], c0);   // 1
      MFMA16(kf[0][kk], qf[1][kk], c1);   // 2^-8
      MFMA16(kf[1][kk], qf[0][kk], c1);   // 2^-8
      MFMA16(kf[1][kk], qf[1][kk], c2);   // 2^-16
      MFMA16(kf[0][kk], qf[2][kk], c2);   // 2^-16
      MFMA16(kf[2][kk], qf[0][kk], c2);   // 2^-16
    }
    const f32x4 c = (c0 + c1) + c2;
    *reinterpret_cast<f32x4*>(
        lds + row * 8192 + ((((t << 2) + lg) ^ key) << 4)) = c;
  };

  // ---- P1: logits. 8 tiles/wave (t = w + 16j), double-buffered.
  {
    bf8 ka[3][2], kb[3][2];
    ldk(w, ka);
#pragma unroll
    for (int j = 0; j < 8; j += 2) {
      const int t0 = w + 16 * j;
      ldk(t0 + 16, kb);
      qk(ka, t0);
      if (j + 2 < 8) ldk(t0 + 32, ka);
      qk(kb, t0 + 16);
    }
  }
  __syncthreads();

  // V prefetch for P3 chunk w (latency hidden under P2)
  bf8 va[4], vb[4];
  auto ldv = [&](int cc, bf8 (&dst)[4]) {
    const short* p = VF + (size_t)(bh * 64 + cc) * 2048 + lane * 8;
    dst[0] = *reinterpret_cast<const bf8*>(p);
    dst[1] = *reinterpret_cast<const bf8*>(p + 512);
    dst[2] = *reinterpret_cast<const bf8*>(p + 1024);
    dst[3] = *reinterpret_cast<const bf8*>(p + 1536);
  };
  ldv(w, va);

  // ---- P2: wave w owns row q=w (q in [0,16)). Verbatim R12 float-space
  // top-64 bisection with ballot/popcount counts.
  {
    const int q = w;
    const int rkey = q & 7;
    const char* rowb = lds + q * 8192;
    float av[32];
    float lm = -3.402823466e+38f;
#pragma unroll
    for (int jj = 0; jj < 8; ++jj) {
      const f32x4 v = *reinterpret_cast<const f32x4*>(rowb + ((lane + 64 * jj) << 4));
#pragma unroll
      for (int e = 0; e < 4; ++e) {
        av[jj * 4 + e] = v[e];
        lm = fmaxf(lm, v[e]);
      }
    }
    // m = global max; g0 = min of per-lane maxima -> cnt(>=g0) >= 64.
    float m = lm, g0 = lm;
#pragma unroll
    for (int off = 32; off; off >>= 1) m = fmaxf(m, __shfl_xor(m, off));
#pragma unroll
    for (int off = 32; off; off >>= 1) g0 = fminf(g0, __shfl_xor(g0, off));
    float ev[32]; float dsum = 0.f;
#pragma unroll
    for (int j = 0; j < 32; ++j) {
      ev[j] = __expf(av[j] - m);
      dsum += ev[j];
    }
#pragma unroll
    for (int off = 32; off; off >>= 1) dsum += __shfl_xor(dsum, off);
    // invariant: cnt(>= lo) >= 64; cnt(>= hi) < 64 (generic case)
    float lo = g0, hi = m;
    for (int it = 0; it < 64; ++it) {
      const float mid = 0.5f * (lo + hi);
      if (!(mid > lo && mid < hi)) break;      // bracket collapsed (ties)
      int cnt = 0;
#pragma unroll
      for (int j = 0; j < 32; ++j)
        cnt += (int)__popcll(__ballot(av[j] >= mid));
      if (cnt >= 64) {
        lo = mid;
        if (cnt == 64) break;                  // gap hit: set is exactly top-64
      } else {
        hi = mid;
      }
    }
    const float thr = lo;
    float ssum = 0.f;
#pragma unroll
    for (int j = 0; j < 32; ++j) ssum += (av[j] >= thr) ? ev[j] : 0.f;
#pragma unroll
    for (int off = 32; off; off >>= 1) ssum += __shfl_xor(ssum, off);
    const float dinv = gate / dsum;
    const float sinv = (1.0f - gate) / ssum;
#pragma unroll
    for (int jj = 0; jj < 8; ++jj) {
      const int p = lane + 64 * jj;
      const int f = p ^ rkey;
      const float w0 = ev[jj*4+0] * (dinv + ((av[jj*4+0] >= thr) ? sinv : 0.f));
      const float w1 = ev[jj*4+1] * (dinv + ((av[jj*4+1] >= thr) ? sinv : 0.f));
      const float w2 = ev[jj*4+2] * (dinv + ((av[jj*4+2] >= thr) ? sinv : 0.f));
      const float w3 = ev[jj*4+3] * (dinv + ((av[jj*4+3] >= thr) ? sinv : 0.f));
      uint2 pk;
      pk.x = pack_bf16x2(w0, w1);
      pk.y = pack_bf16x2(w2, w3);
      *reinterpret_cast<uint2*>(
          lds + q * 8192 + ((((f >> 1) ^ rkey) << 4) + ((f & 1) << 3))) = pk;
    }
  }
  __syncthreads();

  // ---- P3: PV. wave w does s-chunks cc = w + 16j (4 chunks of 32 s), 4 d-tiles.
  f32x4 o0 = {0.f,0.f,0.f,0.f}, o1 = {0.f,0.f,0.f,0.f};
  f32x4 o2 = {0.f,0.f,0.f,0.f}, o3 = {0.f,0.f,0.f,0.f};
  {
    auto pv = [&](bf8 (&vv)[4], int cc) {
      const bf8 pa = *reinterpret_cast<const bf8*>(
          lds + row * 8192 + ((((cc << 2) + lg) ^ key) << 4));
      MFMA16(pa, vv[0], o0);
      MFMA16(pa, vv[1], o1);
      MFMA16(pa, vv[2], o2);
      MFMA16(pa, vv[3], o3);
    };
#pragma unroll
    for (int j = 0; j < 4; j += 2) {
      const int cc = w + 16 * j;
      ldv(cc + 16, vb);
      pv(va, cc);
      if (j + 2 < 4) ldv(cc + 32, va);
      pv(vb, cc + 16);
    }
  }
  // park partials: tile = w*4+dt in [0,64): row tile&15, slot tile>>4
  {
    const f32x4 oo[4] = {o0, o1, o2, o3};
#pragma unroll
    for (int dt = 0; dt < 4; ++dt) {
      const int tile = w * 4 + dt;
      char* pb = lds + (tile & 15) * 8192 + 4096 + ((tile >> 4) << 10);
#pragma unroll
      for (int r = 0; r < 4; ++r)
        *reinterpret_cast<float*>(pb + (((lg * 4 + r) * 16 + lq) << 2)) = oo[dt][r];
    }
  }
  __syncthreads();
  // reduce 16 wave-partials, write HOS (2-level bf16). 1024 thr = 16 q x 64 d.
  {
    const int q = tid >> 6, d = tid & 63;
    const int dt = d >> 4;
    float s = 0.f;
#pragma unroll
    for (int ww = 0; ww < 16; ++ww) {
      const int tile = ww * 4 + dt;
      s += *reinterpret_cast<const float*>(
          lds + (tile & 15) * 8192 + 4096 + ((tile >> 4) << 10) +
          ((q * 16 + (d & 15)) << 2));
    }
    const size_t o = (size_t)(b * TSEQ + q0 + q) * 512 + h * 64 + d;
    const short s1 = f2bf(s);
    HOS[o] = s1;
    HOS[o + 4194304] = f2bf(s - bf2f(s1));
  }
}

// ------------------------------------------------------------------- launcher
extern "C" void kernel_launch(void* const* d_in, const int* in_sizes, int n_in,
                              void* d_out, int out_size, void* d_ws, size_t ws_size,
                              hipStream_t stream) {
  const float* x     = (const float*)d_in[0];
  const float* Wqkv  = (const float*)d_in[1];
  const float* Wout  = (const float*)d_in[2];
  const float* alpha = (const float*)d_in[3];
  float* out = (float*)d_out;

  float* Qf32 = (float*)d_ws;
  short* S16  = (short*)d_ws;
  short* KF   = S16 + 8388608;
  short* VF   = S16 + 20971520;
  short* HOS  = S16 + 25165824;
  short* WoS  = S16 + 33554432;
  short* WqS  = S16 + 34078720;   // 3 x 1536 x 512
  short* XSp  = S16 + 36438016;   // 3 x 8192 x 512

  const int attn_lds = 131072;
  (void)hipFuncSetAttribute((const void*)attn_mfma,
                            hipFuncAttributeMaxDynamicSharedMemorySize, attn_lds);

  transpose_split<<<dim3(4, 16), 256, 0, stream>>>(Wout, WoS, 512, 512);

  const bool big = ws_size >= (size_t)98041856;
  if (big) {
    transpose_split3<<<dim3(12, 16), 256, 0, stream>>>(Wqkv, WqS, 512, 1536);
    xsplit3<<<2048, 256, 0, stream>>>(x, XSp);
    const int qkv_lds = 67584;
    (void)hipFuncSetAttribute((const void*)qkv_mfma,
                              hipFuncAttributeMaxDynamicSharedMemorySize, qkv_lds);
    qkv_mfma<<<dim3(12, 64), 256, qkv_lds, stream>>>(XSp, WqS, Qf32, KF, VF);
  } else {
    qkv_gemm<<<dim3(12, 64), 256, 0, stream>>>(x, Wqkv, Qf32, KF, VF);
  }
  attn_mfma<<<dim3(128, 32), 1024, attn_lds, stream>>>(Qf32, KF, VF, alpha, HOS);
  out_mfma<<<dim3(4, 64), 256, 0, stream>>>(HOS, WoS, out);
}